// Round 1
// baseline (1084.696 us; speedup 1.0000x reference)
//
#include <hip/hip_runtime.h>
#include <hip/hip_bf16.h>
#include <cstdint>

#define HID 1024
#define PAL 3
#define SEQ 256
#define BAT 256
#define BNEPS 1e-5f

typedef __attribute__((ext_vector_type(8))) short short8;
typedef __attribute__((ext_vector_type(4))) float floatx4;

__device__ __forceinline__ ushort f2b(float f) {
  union { float f; uint32_t u; } v; v.f = f;
  uint32_t r = (v.u + 0x7FFFu + ((v.u >> 16) & 1u)) >> 16;
  return (ushort)r;
}

// C[m,n] = sum_k A[m,k]*Bt[n,k] (+bias[n])
// EPI 0: store C (+bias). EPI 1: energy partial epilogue. EPI 2: relu(store).
// GUARDB: scalar guarded B loads (for ldb=1027 / K tail).
template<int EPI, bool GUARDB>
__global__ __launch_bounds__(256, 2)
void gemm_bt(const float* __restrict__ A, int lda,
             const float* __restrict__ Bt, int ldb, int Kb,
             const float* __restrict__ bias,
             float* __restrict__ C, int ldc,
             int M, int K,
             const float* __restrict__ hws,
             const float* __restrict__ enw,
             float* __restrict__ epart)
{
  __shared__ ushort As[128 * 72];
  __shared__ ushort Bs[128 * 72];
  __shared__ float ep[2][128];

  const int tid = threadIdx.x;
  const int lane = tid & 63;
  const int wave = tid >> 6;
  const int wr = (wave >> 1) * 64;
  const int wc = (wave & 1) * 64;
  const int row0 = blockIdx.x * 128;
  const int col0 = blockIdx.y * 128;
  const int rb = tid >> 4;   // 0..15
  const int c4 = tid & 15;   // float4 column index within 64-wide K tile

  floatx4 acc[4][4] = {};

  for (int kt = 0; kt < K; kt += 64) {
    float4 aL[8], bL[8];
#pragma unroll
    for (int it = 0; it < 8; ++it) {
      int r = it * 16 + rb;
      aL[it] = *reinterpret_cast<const float4*>(A + (size_t)(row0 + r) * lda + kt + c4 * 4);
      if (GUARDB) {
        int k0 = kt + c4 * 4;
        const float* bp = Bt + (size_t)(col0 + r) * ldb;
        bL[it].x = (k0 + 0 < Kb) ? bp[k0 + 0] : 0.f;
        bL[it].y = (k0 + 1 < Kb) ? bp[k0 + 1] : 0.f;
        bL[it].z = (k0 + 2 < Kb) ? bp[k0 + 2] : 0.f;
        bL[it].w = (k0 + 3 < Kb) ? bp[k0 + 3] : 0.f;
      } else {
        bL[it] = *reinterpret_cast<const float4*>(Bt + (size_t)(col0 + r) * ldb + kt + c4 * 4);
      }
    }
    __syncthreads();   // previous iteration's LDS reads done
#pragma unroll
    for (int it = 0; it < 8; ++it) {
      int r = it * 16 + rb;
      ushort4 av = make_ushort4(f2b(aL[it].x), f2b(aL[it].y), f2b(aL[it].z), f2b(aL[it].w));
      ushort4 bv = make_ushort4(f2b(bL[it].x), f2b(bL[it].y), f2b(bL[it].z), f2b(bL[it].w));
      *reinterpret_cast<ushort4*>(&As[r * 72 + c4 * 4]) = av;
      *reinterpret_cast<ushort4*>(&Bs[r * 72 + c4 * 4]) = bv;
    }
    __syncthreads();
#pragma unroll
    for (int kk = 0; kk < 2; ++kk) {
      const int ko = (lane >> 4) * 8 + kk * 32;
      short8 af[4], bf[4];
#pragma unroll
      for (int mi = 0; mi < 4; ++mi)
        af[mi] = *reinterpret_cast<const short8*>(&As[(wr + mi * 16 + (lane & 15)) * 72 + ko]);
#pragma unroll
      for (int ni = 0; ni < 4; ++ni)
        bf[ni] = *reinterpret_cast<const short8*>(&Bs[(wc + ni * 16 + (lane & 15)) * 72 + ko]);
#pragma unroll
      for (int mi = 0; mi < 4; ++mi)
#pragma unroll
        for (int ni = 0; ni < 4; ++ni)
          acc[mi][ni] = __builtin_amdgcn_mfma_f32_16x16x32_bf16(af[mi], bf[ni], acc[mi][ni], 0, 0, 0);
    }
  }

  if (EPI == 0 || EPI == 2) {
#pragma unroll
    for (int mi = 0; mi < 4; ++mi) {
      int rloc = wr + mi * 16 + (lane >> 4) * 4;
#pragma unroll
      for (int ni = 0; ni < 4; ++ni) {
        int cg = col0 + wc + ni * 16 + (lane & 15);
        float bv = bias ? bias[cg] : 0.f;
#pragma unroll
        for (int q = 0; q < 4; ++q) {
          float v = acc[mi][ni][q] + bv;
          if (EPI == 2) v = fmaxf(v, 0.f);
          C[(size_t)(row0 + rloc + q) * ldc + cg] = v;
        }
      }
    }
  } else {
    // energy: v = acc + e_b[j] + h[b,j]; partial_energy += sigmoid(v)*en_w[j]
    float rs[4][4];
#pragma unroll
    for (int mi = 0; mi < 4; ++mi) {
#pragma unroll
      for (int q = 0; q < 4; ++q) {
        int m = row0 + wr + mi * 16 + (lane >> 4) * 4 + q;
        int b = m & (BAT - 1);
        float v = 0.f;
#pragma unroll
        for (int ni = 0; ni < 4; ++ni) {
          int cg = col0 + wc + ni * 16 + (lane & 15);
          float e = acc[mi][ni][q] + bias[cg] + hws[(size_t)b * HID + cg];
          float sg = 1.f / (1.f + __expf(-e));
          v += sg * enw[cg];
        }
#pragma unroll
        for (int o = 1; o < 16; o <<= 1) v += __shfl_xor(v, o);
        rs[mi][q] = v;
      }
    }
    if ((lane & 15) == 0) {
#pragma unroll
      for (int mi = 0; mi < 4; ++mi)
#pragma unroll
        for (int q = 0; q < 4; ++q)
          ep[wave & 1][wr + mi * 16 + (lane >> 4) * 4 + q] = rs[mi][q];
    }
    __syncthreads();
    if (tid < 128)
      epart[(size_t)blockIdx.y * M + row0 + tid] = ep[0][tid] + ep[1][tid];
  }
}

__global__ void softmax_kernel(const float* __restrict__ epart,
                               float* __restrict__ wsm, float* __restrict__ att) {
  int b = blockIdx.x, s = threadIdx.x;
  float e = 0.f;
#pragma unroll
  for (int nt = 0; nt < 8; ++nt) e += epart[nt * (SEQ * BAT) + s * BAT + b];
  float m = e;
  for (int o = 1; o < 64; o <<= 1) m = fmaxf(m, __shfl_xor(m, o));
  __shared__ float rm[4], rsum[4];
  if ((s & 63) == 0) rm[s >> 6] = m;
  __syncthreads();
  m = fmaxf(fmaxf(rm[0], rm[1]), fmaxf(rm[2], rm[3]));
  float ex = __expf(e - m);
  float sum = ex;
  for (int o = 1; o < 64; o <<= 1) sum += __shfl_xor(sum, o);
  if ((s & 63) == 0) rsum[s >> 6] = sum;
  __syncthreads();
  sum = rsum[0] + rsum[1] + rsum[2] + rsum[3];
  float w = ex / sum;
  wsm[s * BAT + b] = w;       // [S][B] for context
  att[b * SEQ + s] = w;       // attn_weights output [B,1,S]
}

__global__ void prep_gin(const float* __restrict__ pal, float* __restrict__ gin) {
  int b = threadIdx.x;
  gin[b * 1088 + 0] = pal[b * 3 + 0];
  gin[b * 1088 + 1] = pal[b * 3 + 1];
  gin[b * 1088 + 2] = pal[b * 3 + 2];
  for (int k = 1027; k < 1088; ++k) gin[b * 1088 + k] = 0.f;
}

__global__ void context_kernel(const float* __restrict__ enc, const float* __restrict__ wsm,
                               float* __restrict__ ctx, float* __restrict__ gin) {
  int b = blockIdx.x, hc = blockIdx.y, t = threadIdx.x;
  __shared__ float wl[256];
  wl[t] = wsm[t * BAT + b];
  __syncthreads();
  int h = hc * 256 + t;
  const float* ep = enc + (size_t)b * HID + h;
  float c = 0.f;
#pragma unroll 8
  for (int s = 0; s < SEQ; ++s) c += wl[s] * ep[(size_t)s * BAT * HID];
  ctx[(size_t)b * HID + h] = c;
  gin[b * 1088 + 3 + h] = c;
}

__global__ void gru_combine(const float* __restrict__ gi, const float* __restrict__ gh,
                            const float* __restrict__ hprev, float* __restrict__ hout) {
  int idx = blockIdx.x * 256 + threadIdx.x;
  int b = idx >> 10, j = idx & 1023;
  size_t base = (size_t)b * 3 * HID;
  float ir = gi[base + j], iz = gi[base + HID + j], in_ = gi[base + 2 * HID + j];
  float hr = gh[base + j], hz = gh[base + HID + j], hn = gh[base + 2 * HID + j];
  float r = 1.f / (1.f + __expf(-(ir + hr)));
  float z = 1.f / (1.f + __expf(-(iz + hz)));
  float n = tanhf(in_ + r * hn);
  hout[idx] = (1.f - z) * n + z * hprev[idx];
}

__global__ void bn_stats(const float* __restrict__ x1, const float* __restrict__ bnw,
                         const float* __restrict__ bnb, float* __restrict__ sj,
                         float* __restrict__ tj) {
  int j = blockIdx.x * 256 + threadIdx.x;
  float s = 0.f, ss = 0.f;
  for (int b = 0; b < BAT; ++b) {
    float x = x1[(size_t)b * HID + j];
    s += x; ss += x * x;
  }
  float mu = s * (1.f / BAT);
  float var = ss * (1.f / BAT) - mu * mu;
  float rstd = rsqrtf(var + BNEPS);
  float sc = bnw[j] * rstd;
  sj[j] = sc;
  tj[j] = bnb[j] - mu * sc;
}

__global__ void palette_kernel(const float* __restrict__ x1, const float* __restrict__ sj,
                               const float* __restrict__ tj, const float* __restrict__ w2,
                               const float* __restrict__ b2, float* __restrict__ outp) {
  int b = blockIdx.x, t = threadIdx.x;
  float p0 = 0.f, p1 = 0.f, p2 = 0.f;
  for (int j = t; j < HID; j += 256) {
    float xn = x1[(size_t)b * HID + j] * sj[j] + tj[j];
    p0 += xn * w2[j];
    p1 += xn * w2[HID + j];
    p2 += xn * w2[2 * HID + j];
  }
  for (int o = 1; o < 64; o <<= 1) {
    p0 += __shfl_xor(p0, o); p1 += __shfl_xor(p1, o); p2 += __shfl_xor(p2, o);
  }
  __shared__ float r0[4], r1[4], r2[4];
  int w = t >> 6;
  if ((t & 63) == 0) { r0[w] = p0; r1[w] = p1; r2[w] = p2; }
  __syncthreads();
  if (t == 0) {
    outp[b * 3 + 0] = r0[0] + r0[1] + r0[2] + r0[3] + b2[0];
    outp[b * 3 + 1] = r1[0] + r1[1] + r1[2] + r1[3] + b2[1];
    outp[b * 3 + 2] = r2[0] + r2[1] + r2[2] + r2[3] + b2[2];
  }
}

extern "C" void kernel_launch(void* const* d_in, const int* in_sizes, int n_in,
                              void* d_out, int out_size, void* d_ws, size_t ws_size,
                              hipStream_t stream) {
  const float* pal_in = (const float*)d_in[0];
  const float* ldh    = (const float*)d_in[1];
  const float* enc    = (const float*)d_in[2];
  const float* e_w    = (const float*)d_in[3];
  const float* e_b    = (const float*)d_in[4];
  const float* h_w    = (const float*)d_in[5];
  const float* h_b    = (const float*)d_in[6];
  const float* en_w   = (const float*)d_in[7];
  const float* w_ih   = (const float*)d_in[9];
  const float* w_hh   = (const float*)d_in[10];
  const float* b_ih   = (const float*)d_in[11];
  const float* b_hh   = (const float*)d_in[12];
  const float* o1_w   = (const float*)d_in[13];
  const float* o1_b   = (const float*)d_in[14];
  const float* bnw    = (const float*)d_in[15];
  const float* bnb    = (const float*)d_in[16];
  const float* o2_w   = (const float*)d_in[17];
  const float* o2_b   = (const float*)d_in[18];
  // (attn_en_b is a constant added to every energy -> softmax-invariant, skipped)

  float* out = (float*)d_out;
  float* out_pal = out;                       // [B,3]
  float* out_ctx = out + BAT * PAL;           // [1,B,1,H]
  float* out_hid = out_ctx + BAT * HID;       // [B,H]
  float* out_att = out_hid + BAT * HID;       // [B,1,S]

  float* ws = (float*)d_ws;
  float* hws   = ws;  ws += BAT * HID;        // h projection
  float* epart = ws;  ws += 8 * SEQ * BAT;    // energy partials per N-tile
  float* wsm   = ws;  ws += SEQ * BAT;        // softmax weights [S][B]
  float* gin   = ws;  ws += BAT * 1088;       // padded GRU input
  float* gi    = ws;  ws += BAT * 3 * HID;
  float* gh    = ws;  ws += BAT * 3 * HID;
  float* x1    = ws;  ws += BAT * HID;
  float* sj    = ws;  ws += HID;
  float* tj    = ws;  ws += HID;

  dim3 blk(256);

  // h = ldh @ attn_h_w.T + attn_h_b
  gemm_bt<0, false><<<dim3(2, 8), blk, 0, stream>>>(
      ldh, HID, h_w, HID, HID, h_b, hws, HID, BAT, HID, nullptr, nullptr, nullptr);
  // fused energy partials: sigmoid(enc@e_w.T + e_b + h) . en_w
  gemm_bt<1, false><<<dim3(512, 8), blk, 0, stream>>>(
      enc, HID, e_w, HID, HID, e_b, nullptr, 0, SEQ * BAT, HID, hws, en_w, epart);
  // gh = ldh @ w_hh.T + b_hh  (independent of attention)
  gemm_bt<0, false><<<dim3(2, 24), blk, 0, stream>>>(
      ldh, HID, w_hh, HID, HID, b_hh, gh, 3 * HID, BAT, HID, nullptr, nullptr, nullptr);
  // softmax over s per b
  softmax_kernel<<<dim3(256), blk, 0, stream>>>(epart, wsm, out_att);
  // gru_in: palette cols + zero pad
  prep_gin<<<dim3(1), blk, 0, stream>>>(pal_in, gin);
  // context = sum_s w[s,b]*enc[s,b,:]
  context_kernel<<<dim3(256, 4), blk, 0, stream>>>(enc, wsm, out_ctx, gin);
  // gi = gru_in @ w_ih.T + b_ih   (K padded to 1088, guarded B loads, ldb=1027)
  gemm_bt<0, true><<<dim3(2, 24), blk, 0, stream>>>(
      gin, 1088, w_ih, 1027, 1027, b_ih, gi, 3 * HID, BAT, 1088, nullptr, nullptr, nullptr);
  // GRU combine -> gru_hidden
  gru_combine<<<dim3(1024), blk, 0, stream>>>(gi, gh, ldh, out_hid);
  // x1 = relu(gru_hidden @ out1_w.T + out1_b)
  gemm_bt<2, false><<<dim3(2, 8), blk, 0, stream>>>(
      out_hid, HID, o1_w, HID, HID, o1_b, x1, HID, BAT, HID, nullptr, nullptr, nullptr);
  // batchnorm stats -> scale/shift
  bn_stats<<<dim3(4), blk, 0, stream>>>(x1, bnw, bnb, sj, tj);
  // palette = (x1*s+t) @ out2_w.T + out2_b
  palette_kernel<<<dim3(256), blk, 0, stream>>>(x1, sj, tj, o2_w, o2_b, out_pal);
}

// Round 2
// 453.587 us; speedup vs baseline: 2.3914x; 2.3914x over previous
//
#include <hip/hip_runtime.h>
#include <hip/hip_bf16.h>
#include <cstdint>

#define HID 1024
#define PAL 3
#define SEQ 256
#define BAT 256
#define BNEPS 1e-5f

typedef __attribute__((ext_vector_type(8))) short short8;
typedef __attribute__((ext_vector_type(4))) float floatx4;

__device__ __forceinline__ ushort f2b(float f) {
  union { float f; uint32_t u; } v; v.f = f;
  uint32_t r = (v.u + 0x7FFFu + ((v.u >> 16) & 1u)) >> 16;
  return (ushort)r;
}
__device__ __forceinline__ float b2f(ushort u) {
  union { uint32_t u; float f; } v; v.u = ((uint32_t)u) << 16; return v.f;
}
__device__ __forceinline__ void gl_lds16(const ushort* g, ushort* l) {
  __builtin_amdgcn_global_load_lds(
      (const __attribute__((address_space(1))) void*)g,
      (__attribute__((address_space(3))) void*)l, 16, 0, 0);
}

// ---------------- bf16 GEMM, m97 structure: global_load_lds(16B) + linear LDS ----
// C[m,n] = sum_k A[m,k]*Bt[n,k] (+bias[n]); EPI 0: store, 1: energy, 2: relu-store
template<int EPI>
__global__ __launch_bounds__(256, 2)
void gemm_bf(const ushort* __restrict__ A, int lda,
             const ushort* __restrict__ Bt, int ldb,
             const float* __restrict__ bias,
             float* __restrict__ C, int ldc,
             int M, int K,
             const float* __restrict__ hws,
             const float* __restrict__ enw,
             float* __restrict__ epart)
{
  __shared__ ushort As[128 * 64];
  __shared__ ushort Bs[128 * 64];
  __shared__ float ep[2][128];

  const int tid = threadIdx.x;
  const int lane = tid & 63;
  const int wave = tid >> 6;
  const int wr = (wave >> 1) * 64;
  const int wc = (wave & 1) * 64;
  const int row0 = blockIdx.x * 128;
  const int col0 = blockIdx.y * 128;

  floatx4 acc[4][4] = {};

  for (int kt = 0; kt < K; kt += 64) {
#pragma unroll
    for (int i = 0; i < 4; ++i) {
      int chunk = i * 256 + tid;
      int r = chunk >> 3, c8 = chunk & 7;
      ushort* lbase = (ushort*)As + (size_t)(i * 256 + wave * 64) * 8;
      gl_lds16(A + (size_t)(row0 + r) * lda + kt + c8 * 8, lbase);
      ushort* lbase2 = (ushort*)Bs + (size_t)(i * 256 + wave * 64) * 8;
      gl_lds16(Bt + (size_t)(col0 + r) * ldb + kt + c8 * 8, lbase2);
    }
    __syncthreads();   // drains vmcnt -> tile resident
#pragma unroll
    for (int kk = 0; kk < 2; ++kk) {
      const int ko = (lane >> 4) * 8 + kk * 32;
      short8 af[4], bf[4];
#pragma unroll
      for (int mi = 0; mi < 4; ++mi)
        af[mi] = *reinterpret_cast<const short8*>(&As[(wr + mi * 16 + (lane & 15)) * 64 + ko]);
#pragma unroll
      for (int ni = 0; ni < 4; ++ni)
        bf[ni] = *reinterpret_cast<const short8*>(&Bs[(wc + ni * 16 + (lane & 15)) * 64 + ko]);
#pragma unroll
      for (int mi = 0; mi < 4; ++mi)
#pragma unroll
        for (int ni = 0; ni < 4; ++ni)
          acc[mi][ni] = __builtin_amdgcn_mfma_f32_16x16x32_bf16(af[mi], bf[ni], acc[mi][ni], 0, 0, 0);
    }
    __syncthreads();   // LDS reads done before next stage
  }

  if (EPI == 0 || EPI == 2) {
#pragma unroll
    for (int mi = 0; mi < 4; ++mi) {
      int rloc = wr + mi * 16 + (lane >> 4) * 4;
#pragma unroll
      for (int ni = 0; ni < 4; ++ni) {
        int cg = col0 + wc + ni * 16 + (lane & 15);
        float bv = bias ? bias[cg] : 0.f;
#pragma unroll
        for (int q = 0; q < 4; ++q) {
          float v = acc[mi][ni][q] + bv;
          if (EPI == 2) v = fmaxf(v, 0.f);
          C[(size_t)(row0 + rloc + q) * ldc + cg] = v;
        }
      }
    }
  } else {
    float rs[4][4];
#pragma unroll
    for (int mi = 0; mi < 4; ++mi) {
#pragma unroll
      for (int q = 0; q < 4; ++q) {
        int m = row0 + wr + mi * 16 + (lane >> 4) * 4 + q;
        int b = m & (BAT - 1);
        float v = 0.f;
#pragma unroll
        for (int ni = 0; ni < 4; ++ni) {
          int cg = col0 + wc + ni * 16 + (lane & 15);
          float e = acc[mi][ni][q] + bias[cg] + hws[(size_t)b * HID + cg];
          float sg = 1.f / (1.f + __expf(-e));
          v += sg * enw[cg];
        }
#pragma unroll
        for (int o = 1; o < 16; o <<= 1) v += __shfl_xor(v, o);
        rs[mi][q] = v;
      }
    }
    if ((lane & 15) == 0) {
#pragma unroll
      for (int mi = 0; mi < 4; ++mi)
#pragma unroll
        for (int q = 0; q < 4; ++q)
          ep[wave & 1][wr + mi * 16 + (lane >> 4) * 4 + q] = rs[mi][q];
    }
    __syncthreads();
    if (tid < 128)
      epart[(size_t)blockIdx.y * M + row0 + tid] = ep[0][tid] + ep[1][tid];
  }
}

// ---------------- fp32-input GEMM (round-1 fallback path) ----------------
template<int EPI, bool GUARDB>
__global__ __launch_bounds__(256, 2)
void gemm_bt(const float* __restrict__ A, int lda,
             const float* __restrict__ Bt, int ldb, int Kb,
             const float* __restrict__ bias,
             float* __restrict__ C, int ldc,
             int M, int K,
             const float* __restrict__ hws,
             const float* __restrict__ enw,
             float* __restrict__ epart)
{
  __shared__ ushort As[128 * 72];
  __shared__ ushort Bs[128 * 72];
  __shared__ float ep[2][128];

  const int tid = threadIdx.x;
  const int lane = tid & 63;
  const int wave = tid >> 6;
  const int wr = (wave >> 1) * 64;
  const int wc = (wave & 1) * 64;
  const int row0 = blockIdx.x * 128;
  const int col0 = blockIdx.y * 128;
  const int rb = tid >> 4;
  const int c4 = tid & 15;

  floatx4 acc[4][4] = {};

  for (int kt = 0; kt < K; kt += 64) {
    float4 aL[8], bL[8];
#pragma unroll
    for (int it = 0; it < 8; ++it) {
      int r = it * 16 + rb;
      aL[it] = *reinterpret_cast<const float4*>(A + (size_t)(row0 + r) * lda + kt + c4 * 4);
      if (GUARDB) {
        int k0 = kt + c4 * 4;
        const float* bp = Bt + (size_t)(col0 + r) * ldb;
        bL[it].x = (k0 + 0 < Kb) ? bp[k0 + 0] : 0.f;
        bL[it].y = (k0 + 1 < Kb) ? bp[k0 + 1] : 0.f;
        bL[it].z = (k0 + 2 < Kb) ? bp[k0 + 2] : 0.f;
        bL[it].w = (k0 + 3 < Kb) ? bp[k0 + 3] : 0.f;
      } else {
        bL[it] = *reinterpret_cast<const float4*>(Bt + (size_t)(col0 + r) * ldb + kt + c4 * 4);
      }
    }
    __syncthreads();
#pragma unroll
    for (int it = 0; it < 8; ++it) {
      int r = it * 16 + rb;
      ushort4 av = make_ushort4(f2b(aL[it].x), f2b(aL[it].y), f2b(aL[it].z), f2b(aL[it].w));
      ushort4 bv = make_ushort4(f2b(bL[it].x), f2b(bL[it].y), f2b(bL[it].z), f2b(bL[it].w));
      *reinterpret_cast<ushort4*>(&As[r * 72 + c4 * 4]) = av;
      *reinterpret_cast<ushort4*>(&Bs[r * 72 + c4 * 4]) = bv;
    }
    __syncthreads();
#pragma unroll
    for (int kk = 0; kk < 2; ++kk) {
      const int ko = (lane >> 4) * 8 + kk * 32;
      short8 af[4], bf[4];
#pragma unroll
      for (int mi = 0; mi < 4; ++mi)
        af[mi] = *reinterpret_cast<const short8*>(&As[(wr + mi * 16 + (lane & 15)) * 72 + ko]);
#pragma unroll
      for (int ni = 0; ni < 4; ++ni)
        bf[ni] = *reinterpret_cast<const short8*>(&Bs[(wc + ni * 16 + (lane & 15)) * 72 + ko]);
#pragma unroll
      for (int mi = 0; mi < 4; ++mi)
#pragma unroll
        for (int ni = 0; ni < 4; ++ni)
          acc[mi][ni] = __builtin_amdgcn_mfma_f32_16x16x32_bf16(af[mi], bf[ni], acc[mi][ni], 0, 0, 0);
    }
  }

  if (EPI == 0 || EPI == 2) {
#pragma unroll
    for (int mi = 0; mi < 4; ++mi) {
      int rloc = wr + mi * 16 + (lane >> 4) * 4;
#pragma unroll
      for (int ni = 0; ni < 4; ++ni) {
        int cg = col0 + wc + ni * 16 + (lane & 15);
        float bv = bias ? bias[cg] : 0.f;
#pragma unroll
        for (int q = 0; q < 4; ++q) {
          float v = acc[mi][ni][q] + bv;
          if (EPI == 2) v = fmaxf(v, 0.f);
          C[(size_t)(row0 + rloc + q) * ldc + cg] = v;
        }
      }
    }
  } else {
    float rs[4][4];
#pragma unroll
    for (int mi = 0; mi < 4; ++mi) {
#pragma unroll
      for (int q = 0; q < 4; ++q) {
        int m = row0 + wr + mi * 16 + (lane >> 4) * 4 + q;
        int b = m & (BAT - 1);
        float v = 0.f;
#pragma unroll
        for (int ni = 0; ni < 4; ++ni) {
          int cg = col0 + wc + ni * 16 + (lane & 15);
          float e = acc[mi][ni][q] + bias[cg] + hws[(size_t)b * HID + cg];
          float sg = 1.f / (1.f + __expf(-e));
          v += sg * enw[cg];
        }
#pragma unroll
        for (int o = 1; o < 16; o <<= 1) v += __shfl_xor(v, o);
        rs[mi][q] = v;
      }
    }
    if ((lane & 15) == 0) {
#pragma unroll
      for (int mi = 0; mi < 4; ++mi)
#pragma unroll
        for (int q = 0; q < 4; ++q)
          ep[wave & 1][wr + mi * 16 + (lane >> 4) * 4 + q] = rs[mi][q];
    }
    __syncthreads();
    if (tid < 128)
      epart[(size_t)blockIdx.y * M + row0 + tid] = ep[0][tid] + ep[1][tid];
  }
}

// ---------------- conversion kernels ----------------
__global__ void f2b_kernel(const float* __restrict__ in, ushort* __restrict__ out, size_t n) {
  size_t i = ((size_t)blockIdx.x * 256 + threadIdx.x) * 8;
  if (i + 8 > n) return;
  float4 a = *reinterpret_cast<const float4*>(in + i);
  float4 b = *reinterpret_cast<const float4*>(in + i + 4);
  ushort o[8] = {f2b(a.x), f2b(a.y), f2b(a.z), f2b(a.w),
                 f2b(b.x), f2b(b.y), f2b(b.z), f2b(b.w)};
  *reinterpret_cast<short8*>(out + i) = *reinterpret_cast<short8*>(o);
}

__global__ void pack_wih(const float* __restrict__ in, ushort* __restrict__ out) {
  int r = blockIdx.x;
  int c = blockIdx.y * 256 + threadIdx.x;
  if (c < 1088)
    out[(size_t)r * 1088 + c] = (c < 1027) ? f2b(in[(size_t)r * 1027 + c]) : (ushort)0;
}

// ---------------- small fused kernels ----------------
__global__ void softmax_kernel(const float* __restrict__ epart,
                               float* __restrict__ wsm, float* __restrict__ att) {
  int b = blockIdx.x, s = threadIdx.x;
  float e = 0.f;
#pragma unroll
  for (int nt = 0; nt < 8; ++nt) e += epart[nt * (SEQ * BAT) + s * BAT + b];
  float m = e;
  for (int o = 1; o < 64; o <<= 1) m = fmaxf(m, __shfl_xor(m, o));
  __shared__ float rm[4], rsum[4];
  if ((s & 63) == 0) rm[s >> 6] = m;
  __syncthreads();
  m = fmaxf(fmaxf(rm[0], rm[1]), fmaxf(rm[2], rm[3]));
  float ex = __expf(e - m);
  float sum = ex;
  for (int o = 1; o < 64; o <<= 1) sum += __shfl_xor(sum, o);
  if ((s & 63) == 0) rsum[s >> 6] = sum;
  __syncthreads();
  sum = rsum[0] + rsum[1] + rsum[2] + rsum[3];
  float w = ex / sum;
  wsm[s * BAT + b] = w;
  att[b * SEQ + s] = w;
}

__global__ void prep_gin_bf(const float* __restrict__ pal, ushort* __restrict__ ginb) {
  int b = threadIdx.x;
  ginb[b * 1088 + 0] = f2b(pal[b * 3 + 0]);
  ginb[b * 1088 + 1] = f2b(pal[b * 3 + 1]);
  ginb[b * 1088 + 2] = f2b(pal[b * 3 + 2]);
  for (int k = 1027; k < 1088; ++k) ginb[b * 1088 + k] = 0;
}

__global__ void prep_gin(const float* __restrict__ pal, float* __restrict__ gin) {
  int b = threadIdx.x;
  gin[b * 1088 + 0] = pal[b * 3 + 0];
  gin[b * 1088 + 1] = pal[b * 3 + 1];
  gin[b * 1088 + 2] = pal[b * 3 + 2];
  for (int k = 1027; k < 1088; ++k) gin[b * 1088 + k] = 0.f;
}

// context from bf16 enc; writes fp32 ctx output and bf16 gin column
__global__ void context_bf(const ushort* __restrict__ encb, const float* __restrict__ wsm,
                           float* __restrict__ ctx, ushort* __restrict__ ginb) {
  int b = blockIdx.x, hc = blockIdx.y, t = threadIdx.x;
  __shared__ float wl[256];
  wl[t] = wsm[t * BAT + b];
  __syncthreads();
  int h = hc * 256 + t;
  const ushort* ep = encb + (size_t)b * HID + h;
  float c = 0.f;
#pragma unroll 8
  for (int s = 0; s < SEQ; ++s) c += wl[s] * b2f(ep[(size_t)s * BAT * HID]);
  ctx[(size_t)b * HID + h] = c;
  ginb[b * 1088 + 3 + h] = f2b(c);
}

__global__ void context_kernel(const float* __restrict__ enc, const float* __restrict__ wsm,
                               float* __restrict__ ctx, float* __restrict__ gin) {
  int b = blockIdx.x, hc = blockIdx.y, t = threadIdx.x;
  __shared__ float wl[256];
  wl[t] = wsm[t * BAT + b];
  __syncthreads();
  int h = hc * 256 + t;
  const float* ep = enc + (size_t)b * HID + h;
  float c = 0.f;
#pragma unroll 8
  for (int s = 0; s < SEQ; ++s) c += wl[s] * ep[(size_t)s * BAT * HID];
  ctx[(size_t)b * HID + h] = c;
  gin[b * 1088 + 3 + h] = c;
}

__global__ void gru_combine(const float* __restrict__ gi, const float* __restrict__ gh,
                            const float* __restrict__ hprev, float* __restrict__ hout,
                            ushort* __restrict__ hb) {
  int idx = blockIdx.x * 256 + threadIdx.x;
  int b = idx >> 10, j = idx & 1023;
  size_t base = (size_t)b * 3 * HID;
  float ir = gi[base + j], iz = gi[base + HID + j], in_ = gi[base + 2 * HID + j];
  float hr = gh[base + j], hz = gh[base + HID + j], hn = gh[base + 2 * HID + j];
  float r = 1.f / (1.f + __expf(-(ir + hr)));
  float z = 1.f / (1.f + __expf(-(iz + hz)));
  float n = tanhf(in_ + r * hn);
  float v = (1.f - z) * n + z * hprev[idx];
  hout[idx] = v;
  if (hb) hb[idx] = f2b(v);
}

__global__ void bn_stats(const float* __restrict__ x1, const float* __restrict__ bnw,
                         const float* __restrict__ bnb, float* __restrict__ sj,
                         float* __restrict__ tj) {
  int j = blockIdx.x * 256 + threadIdx.x;
  float s = 0.f, ss = 0.f;
  for (int b = 0; b < BAT; ++b) {
    float x = x1[(size_t)b * HID + j];
    s += x; ss += x * x;
  }
  float mu = s * (1.f / BAT);
  float var = ss * (1.f / BAT) - mu * mu;
  float rstd = rsqrtf(var + BNEPS);
  float sc = bnw[j] * rstd;
  sj[j] = sc;
  tj[j] = bnb[j] - mu * sc;
}

__global__ void palette_kernel(const float* __restrict__ x1, const float* __restrict__ sj,
                               const float* __restrict__ tj, const float* __restrict__ w2,
                               const float* __restrict__ b2, float* __restrict__ outp) {
  int b = blockIdx.x, t = threadIdx.x;
  float p0 = 0.f, p1 = 0.f, p2 = 0.f;
  for (int j = t; j < HID; j += 256) {
    float xn = x1[(size_t)b * HID + j] * sj[j] + tj[j];
    p0 += xn * w2[j];
    p1 += xn * w2[HID + j];
    p2 += xn * w2[2 * HID + j];
  }
  for (int o = 1; o < 64; o <<= 1) {
    p0 += __shfl_xor(p0, o); p1 += __shfl_xor(p1, o); p2 += __shfl_xor(p2, o);
  }
  __shared__ float r0[4], r1[4], r2[4];
  int w = t >> 6;
  if ((t & 63) == 0) { r0[w] = p0; r1[w] = p1; r2[w] = p2; }
  __syncthreads();
  if (t == 0) {
    outp[b * 3 + 0] = r0[0] + r0[1] + r0[2] + r0[3] + b2[0];
    outp[b * 3 + 1] = r1[0] + r1[1] + r1[2] + r1[3] + b2[1];
    outp[b * 3 + 2] = r2[0] + r2[1] + r2[2] + r2[3] + b2[2];
  }
}

extern "C" void kernel_launch(void* const* d_in, const int* in_sizes, int n_in,
                              void* d_out, int out_size, void* d_ws, size_t ws_size,
                              hipStream_t stream) {
  const float* pal_in = (const float*)d_in[0];
  const float* ldh    = (const float*)d_in[1];
  const float* enc    = (const float*)d_in[2];
  const float* e_w    = (const float*)d_in[3];
  const float* e_b    = (const float*)d_in[4];
  const float* h_w    = (const float*)d_in[5];
  const float* h_b    = (const float*)d_in[6];
  const float* en_w   = (const float*)d_in[7];
  const float* w_ih   = (const float*)d_in[9];
  const float* w_hh   = (const float*)d_in[10];
  const float* b_ih   = (const float*)d_in[11];
  const float* b_hh   = (const float*)d_in[12];
  const float* o1_w   = (const float*)d_in[13];
  const float* o1_b   = (const float*)d_in[14];
  const float* bnw    = (const float*)d_in[15];
  const float* bnb    = (const float*)d_in[16];
  const float* o2_w   = (const float*)d_in[17];
  const float* o2_b   = (const float*)d_in[18];

  float* out = (float*)d_out;
  float* out_pal = out;
  float* out_ctx = out + BAT * PAL;
  float* out_hid = out_ctx + BAT * HID;
  float* out_att = out_hid + BAT * HID;

  dim3 blk(256);

  // ---- carve bf16-path workspace ----
  char* p0 = (char*)d_ws;
  char* p = p0;
  auto carve = [&](size_t bytes) { char* r = p; p += (bytes + 255) & ~(size_t)255; return r; };
  ushort* enc_bf = (ushort*)carve((size_t)SEQ * BAT * HID * 2);
  ushort* ew_bf  = (ushort*)carve((size_t)HID * HID * 2);
  ushort* hw_bf  = (ushort*)carve((size_t)HID * HID * 2);
  ushort* whh_bf = (ushort*)carve((size_t)3 * HID * HID * 2);
  ushort* wih_bf = (ushort*)carve((size_t)3 * HID * 1088 * 2);
  ushort* o1_bf  = (ushort*)carve((size_t)HID * HID * 2);
  ushort* ldh_bf = (ushort*)carve((size_t)BAT * HID * 2);
  ushort* gin_bf = (ushort*)carve((size_t)BAT * 1088 * 2);
  ushort* hid_bf = (ushort*)carve((size_t)BAT * HID * 2);
  float* hws   = (float*)carve((size_t)BAT * HID * 4);
  float* epart = (float*)carve((size_t)8 * SEQ * BAT * 4);
  float* wsm   = (float*)carve((size_t)SEQ * BAT * 4);
  float* gi    = (float*)carve((size_t)BAT * 3 * HID * 4);
  float* gh    = (float*)carve((size_t)BAT * 3 * HID * 4);
  float* x1    = (float*)carve((size_t)BAT * HID * 4);
  float* sj    = (float*)carve((size_t)HID * 4);
  float* tj    = (float*)carve((size_t)HID * 4);
  size_t need = (size_t)(p - p0);

  if (ws_size >= need) {
    // -------- bf16 fast path --------
    // small conversions first
    f2b_kernel<<<dim3((BAT * HID) / 2048), blk, 0, stream>>>(ldh, ldh_bf, (size_t)BAT * HID);
    f2b_kernel<<<dim3((HID * HID) / 2048), blk, 0, stream>>>(h_w, hw_bf, (size_t)HID * HID);
    f2b_kernel<<<dim3((HID * HID) / 2048), blk, 0, stream>>>(e_w, ew_bf, (size_t)HID * HID);
    f2b_kernel<<<dim3((3 * HID * HID) / 2048), blk, 0, stream>>>(w_hh, whh_bf, (size_t)3 * HID * HID);
    f2b_kernel<<<dim3((HID * HID) / 2048), blk, 0, stream>>>(o1_w, o1_bf, (size_t)HID * HID);
    pack_wih<<<dim3(3 * HID, 5), blk, 0, stream>>>(w_ih, wih_bf);
    prep_gin_bf<<<dim3(1), blk, 0, stream>>>(pal_in, gin_bf);
    // h = ldh @ h_w.T + h_b  (needed by energy epilogue)
    gemm_bf<0><<<dim3(2, 8), blk, 0, stream>>>(
        ldh_bf, HID, hw_bf, HID, h_b, hws, HID, BAT, HID, nullptr, nullptr, nullptr);
    // big conversion: enc -> bf16
    f2b_kernel<<<dim3((SEQ * BAT * HID) / 2048), blk, 0, stream>>>(enc, enc_bf, (size_t)SEQ * BAT * HID);
    // fused energy partials
    gemm_bf<1><<<dim3(512, 8), blk, 0, stream>>>(
        enc_bf, HID, ew_bf, HID, e_b, nullptr, 0, SEQ * BAT, HID, hws, en_w, epart);
    // gh (independent of attention)
    gemm_bf<0><<<dim3(2, 24), blk, 0, stream>>>(
        ldh_bf, HID, whh_bf, HID, b_hh, gh, 3 * HID, BAT, HID, nullptr, nullptr, nullptr);
    softmax_kernel<<<dim3(256), blk, 0, stream>>>(epart, wsm, out_att);
    context_bf<<<dim3(256, 4), blk, 0, stream>>>(enc_bf, wsm, out_ctx, gin_bf);
    // gi = gin @ w_ih.T + b_ih  (K padded to 1088, both operands zero-padded)
    gemm_bf<0><<<dim3(2, 24), blk, 0, stream>>>(
        gin_bf, 1088, wih_bf, 1088, b_ih, gi, 3 * HID, BAT, 1088, nullptr, nullptr, nullptr);
    gru_combine<<<dim3(1024), blk, 0, stream>>>(gi, gh, ldh, out_hid, hid_bf);
    gemm_bf<2><<<dim3(2, 8), blk, 0, stream>>>(
        hid_bf, HID, o1_bf, HID, o1_b, x1, HID, BAT, HID, nullptr, nullptr, nullptr);
    bn_stats<<<dim3(4), blk, 0, stream>>>(x1, bnw, bnb, sj, tj);
    palette_kernel<<<dim3(256), blk, 0, stream>>>(x1, sj, tj, o2_w, o2_b, out_pal);
  } else {
    // -------- round-1 fp32 fallback path --------
    char* q = p0;
    auto carve2 = [&](size_t bytes) { char* r = q; q += (bytes + 255) & ~(size_t)255; return r; };
    float* hws2   = (float*)carve2((size_t)BAT * HID * 4);
    float* epart2 = (float*)carve2((size_t)8 * SEQ * BAT * 4);
    float* wsm2   = (float*)carve2((size_t)SEQ * BAT * 4);
    float* gin2   = (float*)carve2((size_t)BAT * 1088 * 4);
    float* gi2    = (float*)carve2((size_t)BAT * 3 * HID * 4);
    float* gh2    = (float*)carve2((size_t)BAT * 3 * HID * 4);
    float* x12    = (float*)carve2((size_t)BAT * HID * 4);
    float* sj2    = (float*)carve2((size_t)HID * 4);
    float* tj2    = (float*)carve2((size_t)HID * 4);

    gemm_bt<0, false><<<dim3(2, 8), blk, 0, stream>>>(
        ldh, HID, h_w, HID, HID, h_b, hws2, HID, BAT, HID, nullptr, nullptr, nullptr);
    gemm_bt<1, false><<<dim3(512, 8), blk, 0, stream>>>(
        enc, HID, e_w, HID, HID, e_b, nullptr, 0, SEQ * BAT, HID, hws2, en_w, epart2);
    gemm_bt<0, false><<<dim3(2, 24), blk, 0, stream>>>(
        ldh, HID, w_hh, HID, HID, b_hh, gh2, 3 * HID, BAT, HID, nullptr, nullptr, nullptr);
    softmax_kernel<<<dim3(256), blk, 0, stream>>>(epart2, wsm2, out_att);
    prep_gin<<<dim3(1), blk, 0, stream>>>(pal_in, gin2);
    context_kernel<<<dim3(256, 4), blk, 0, stream>>>(enc, wsm2, out_ctx, gin2);
    gemm_bt<0, true><<<dim3(2, 24), blk, 0, stream>>>(
        gin2, 1088, w_ih, 1027, 1027, b_ih, gi2, 3 * HID, BAT, 1088, nullptr, nullptr, nullptr);
    gru_combine<<<dim3(1024), blk, 0, stream>>>(gi2, gh2, ldh, out_hid, nullptr);
    gemm_bt<2, false><<<dim3(2, 8), blk, 0, stream>>>(
        out_hid, HID, o1_w, HID, HID, o1_b, x12, HID, BAT, HID, nullptr, nullptr, nullptr);
    bn_stats<<<dim3(4), blk, 0, stream>>>(x12, bnw, bnb, sj2, tj2);
    palette_kernel<<<dim3(256), blk, 0, stream>>>(x12, sj2, tj2, o2_w, o2_b, out_pal);
  }
}

// Round 3
// 452.166 us; speedup vs baseline: 2.3989x; 1.0031x over previous
//
#include <hip/hip_runtime.h>
#include <hip/hip_bf16.h>
#include <cstdint>

#define HID 1024
#define PAL 3
#define SEQ 256
#define BAT 256
#define BNEPS 1e-5f

typedef __attribute__((ext_vector_type(8))) short short8;
typedef __attribute__((ext_vector_type(4))) float floatx4;

__device__ __forceinline__ ushort f2b(float f) {
  union { float f; uint32_t u; } v; v.f = f;
  uint32_t r = (v.u + 0x7FFFu + ((v.u >> 16) & 1u)) >> 16;
  return (ushort)r;
}
__device__ __forceinline__ float b2f(ushort u) {
  union { uint32_t u; float f; } v; v.u = ((uint32_t)u) << 16; return v.f;
}
__device__ __forceinline__ void gl_lds16(const ushort* g, ushort* l) {
  __builtin_amdgcn_global_load_lds(
      (const __attribute__((address_space(1))) void*)g,
      (__attribute__((address_space(3))) void*)l, 16, 0, 0);
}
__device__ __forceinline__ void cfence() { asm volatile("" ::: "memory"); }

// ================= 256x256 8-phase energy GEMM (m201 structure) ================
// A: [M][K] bf16 (enc), Bt: [N][K] bf16 (e_w). Computes per-row energy partials:
// epart[ct*M + m] = sum_{col in tile ct} sigmoid(A@Bt.T + e_b[col] + hws[b][col]) * enw[col]
// Schedule per K-tile t (4 phases, 16 MFMA each):
//   ph0: read bf(t)[8] + af01(t)[4]; stage A(t+1)H0          -> Abuf[t^1]
//   ph1: read af23(t);               stage A(t+1)H1          -> Abuf[t^1]
//   ph2: read af45(t);               stage B(t+2)H0          -> Bbuf[t]   (B(t) dead after ph0)
//   ph3: read af67(t);               stage B(t+2)H1; vmcnt(4)
// vmcnt(4): entering tile with 4 outstanding (B(t+1)); +8 issued this tile = 12;
// wait->4 leaves exactly B(t+2) in flight; oldest 8 = B(t+1)+A(t+1) landed = next tile's needs.
// LDS swizzle (T2, rule #21 both-sides): linear dest, source chunk c8 ^= (row&7),
// read chunk kc ^= (row&7) -> 2-way bank aliasing (free per m136).
template<int NT>
__global__ __launch_bounds__(512, 1)
void gemm256_energy(const ushort* __restrict__ A, const ushort* __restrict__ Bt,
                    const float* __restrict__ e_b, const float* __restrict__ hws, int ldh,
                    const float* __restrict__ enw, float* __restrict__ epart, int M)
{
  __shared__ ushort A_s[2][2][128 * 64];
  __shared__ ushort B_s[2][2][128 * 64];
  const int K = NT * 64;
  const int tid = threadIdx.x;
  const int lane = tid & 63;
  const int wave = tid >> 6;
  const int l15 = lane & 15;
  const int wm = wave >> 2, wn = wave & 3;

  // T1: bijective XCD swizzle (nwg divisible by 8)
  int bid = blockIdx.x;
  int swz = (bid & 7) * ((int)gridDim.x >> 3) + (bid >> 3);
  int rt = swz >> 2, ct = swz & 3;
  const int row0 = rt * 256, col0 = ct * 256;

  auto stageA = [&](int t, int h) {
#pragma unroll
    for (int j = 0; j < 2; ++j) {
      int cidx = j * 512 + tid;
      int r = cidx >> 3, c8 = cidx & 7;
      const ushort* src = A + (size_t)(row0 + h * 128 + r) * K + t * 64 + ((c8 ^ (r & 7)) << 3);
      gl_lds16(src, &A_s[t & 1][h][(size_t)(j * 512 + wave * 64) * 8]);
    }
  };
  auto stageB = [&](int t, int h) {
#pragma unroll
    for (int j = 0; j < 2; ++j) {
      int cidx = j * 512 + tid;
      int r = cidx >> 3, c8 = cidx & 7;
      const ushort* src = Bt + (size_t)(col0 + h * 128 + r) * K + t * 64 + ((c8 ^ (r & 7)) << 3);
      gl_lds16(src, &B_s[t & 1][h][(size_t)(j * 512 + wave * 64) * 8]);
    }
  };
  auto readA = [&](int b, int mi, int kh) -> short8 {
    int row = mi * 16 + l15;
    int kc = (lane >> 4) + kh * 4;
    return *reinterpret_cast<const short8*>(&A_s[b][wm][row * 64 + ((kc ^ (row & 7)) << 3)]);
  };
  auto readB = [&](int b, int ni, int kh) -> short8 {
    int rr = (wn & 1) * 64 + ni * 16 + l15;
    int kc = (lane >> 4) + kh * 4;
    return *reinterpret_cast<const short8*>(&B_s[b][wn >> 1][rr * 64 + ((kc ^ (rr & 7)) << 3)]);
  };

  floatx4 acc[8][4] = {};

  // prologue: A(0), B(0), B(1) in flight; wait A0,B0 (oldest 8), keep B(1) (4) counted
  stageA(0, 0); stageA(0, 1);
  stageB(0, 0); stageB(0, 1);
  if (NT > 1) { stageB(1, 0); stageB(1, 1); }
  if (NT > 1) asm volatile("s_waitcnt vmcnt(4)" ::: "memory");
  else        asm volatile("s_waitcnt vmcnt(0)" ::: "memory");
  cfence(); __builtin_amdgcn_s_barrier(); cfence();

  for (int t = 0; t < NT; ++t) {
    const int b = t & 1;
    short8 bf[4][2];
#pragma unroll
    for (int g = 0; g < 4; ++g) {
      short8 af[2][2];
      if (g == 0) {
#pragma unroll
        for (int ni = 0; ni < 4; ++ni) { bf[ni][0] = readB(b, ni, 0); bf[ni][1] = readB(b, ni, 1); }
      }
#pragma unroll
      for (int mi = 0; mi < 2; ++mi) {
        af[mi][0] = readA(b, g * 2 + mi, 0);
        af[mi][1] = readA(b, g * 2 + mi, 1);
      }
      if (g == 0)      { if (t + 1 < NT) stageA(t + 1, 0); }
      else if (g == 1) { if (t + 1 < NT) stageA(t + 1, 1); }
      else if (g == 2) { if (t + 2 < NT) stageB(t + 2, 0); }
      else             { if (t + 2 < NT) stageB(t + 2, 1); }
      cfence(); __builtin_amdgcn_s_barrier(); cfence();
      __builtin_amdgcn_s_setprio(1);
#pragma unroll
      for (int mi = 0; mi < 2; ++mi)
#pragma unroll
        for (int ni = 0; ni < 4; ++ni)
#pragma unroll
          for (int kh = 0; kh < 2; ++kh)
            acc[g * 2 + mi][ni] = __builtin_amdgcn_mfma_f32_16x16x32_bf16(
                af[mi][kh], bf[ni][kh], acc[g * 2 + mi][ni], 0, 0, 0);
      __builtin_amdgcn_s_setprio(0);
      if (g == 3) {
        if (t + 2 < NT) asm volatile("s_waitcnt vmcnt(4)" ::: "memory");
        else            asm volatile("s_waitcnt vmcnt(0)" ::: "memory");
      }
      cfence(); __builtin_amdgcn_s_barrier(); cfence();
    }
  }

  // ---- energy epilogue: per-row sum over this block's 256 cols ----
  __syncthreads();                       // all LDS traffic drained; repurpose A_s
  float* epl = (float*)&A_s[0][0][0];    // [8 waves][128 rows]
#pragma unroll
  for (int mi = 0; mi < 8; ++mi)
#pragma unroll
    for (int q = 0; q < 4; ++q) {
      int rl = wm * 128 + mi * 16 + (lane >> 4) * 4 + q;  // row_local == batch index
      float v = 0.f;
#pragma unroll
      for (int ni = 0; ni < 4; ++ni) {
        int cg = col0 + wn * 64 + ni * 16 + l15;
        float e = acc[mi][ni][q] + e_b[cg] + hws[(size_t)rl * ldh + cg];
        v += enw[cg] * (1.f / (1.f + __expf(-e)));
      }
#pragma unroll
      for (int o = 1; o < 16; o <<= 1) v += __shfl_xor(v, o);
      if (l15 == 0) epl[(wm * 4 + wn) * 128 + mi * 16 + (lane >> 4) * 4 + q] = v;
    }
  __syncthreads();
  if (tid < 256) {
    int wmm = tid >> 7, r = tid & 127;
    float s = 0.f;
#pragma unroll
    for (int w = 0; w < 4; ++w) s += epl[(wmm * 4 + w) * 128 + r];
    epart[(size_t)ct * M + row0 + tid] = s;
  }
}

// ---------------- bf16 GEMM, m97 structure (small GEMMs) ----------------
template<int EPI>
__global__ __launch_bounds__(256, 2)
void gemm_bf(const ushort* __restrict__ A, int lda,
             const ushort* __restrict__ Bt, int ldb,
             const float* __restrict__ bias,
             float* __restrict__ C, int ldc,
             int M, int K)
{
  __shared__ ushort As[128 * 64];
  __shared__ ushort Bs[128 * 64];

  const int tid = threadIdx.x;
  const int lane = tid & 63;
  const int wave = tid >> 6;
  const int wr = (wave >> 1) * 64;
  const int wc = (wave & 1) * 64;
  const int row0 = blockIdx.x * 128;
  const int col0 = blockIdx.y * 128;

  floatx4 acc[4][4] = {};

  for (int kt = 0; kt < K; kt += 64) {
#pragma unroll
    for (int i = 0; i < 4; ++i) {
      int chunk = i * 256 + tid;
      int r = chunk >> 3, c8 = chunk & 7;
      gl_lds16(A + (size_t)(row0 + r) * lda + kt + c8 * 8,
               (ushort*)As + (size_t)(i * 256 + wave * 64) * 8);
      gl_lds16(Bt + (size_t)(col0 + r) * ldb + kt + c8 * 8,
               (ushort*)Bs + (size_t)(i * 256 + wave * 64) * 8);
    }
    __syncthreads();
#pragma unroll
    for (int kk = 0; kk < 2; ++kk) {
      const int ko = (lane >> 4) * 8 + kk * 32;
      short8 af[4], bf[4];
#pragma unroll
      for (int mi = 0; mi < 4; ++mi)
        af[mi] = *reinterpret_cast<const short8*>(&As[(wr + mi * 16 + (lane & 15)) * 64 + ko]);
#pragma unroll
      for (int ni = 0; ni < 4; ++ni)
        bf[ni] = *reinterpret_cast<const short8*>(&Bs[(wc + ni * 16 + (lane & 15)) * 64 + ko]);
#pragma unroll
      for (int mi = 0; mi < 4; ++mi)
#pragma unroll
        for (int ni = 0; ni < 4; ++ni)
          acc[mi][ni] = __builtin_amdgcn_mfma_f32_16x16x32_bf16(af[mi], bf[ni], acc[mi][ni], 0, 0, 0);
    }
    __syncthreads();
  }

#pragma unroll
  for (int mi = 0; mi < 4; ++mi) {
    int rloc = wr + mi * 16 + (lane >> 4) * 4;
#pragma unroll
    for (int ni = 0; ni < 4; ++ni) {
      int cg = col0 + wc + ni * 16 + (lane & 15);
      float bv = bias ? bias[cg] : 0.f;
#pragma unroll
      for (int q = 0; q < 4; ++q) {
        float v = acc[mi][ni][q] + bv;
        if (EPI == 2) v = fmaxf(v, 0.f);
        C[(size_t)(row0 + rloc + q) * ldc + cg] = v;
      }
    }
  }
}

// ---------------- fp32-input GEMM (fallback path only) ----------------
template<int EPI, bool GUARDB>
__global__ __launch_bounds__(256, 2)
void gemm_bt(const float* __restrict__ A, int lda,
             const float* __restrict__ Bt, int ldb, int Kb,
             const float* __restrict__ bias,
             float* __restrict__ C, int ldc,
             int M, int K,
             const float* __restrict__ hws,
             const float* __restrict__ enw,
             float* __restrict__ epart)
{
  __shared__ ushort As[128 * 72];
  __shared__ ushort Bs[128 * 72];
  __shared__ float ep[2][128];

  const int tid = threadIdx.x;
  const int lane = tid & 63;
  const int wave = tid >> 6;
  const int wr = (wave >> 1) * 64;
  const int wc = (wave & 1) * 64;
  const int row0 = blockIdx.x * 128;
  const int col0 = blockIdx.y * 128;
  const int rb = tid >> 4;
  const int c4 = tid & 15;

  floatx4 acc[4][4] = {};

  for (int kt = 0; kt < K; kt += 64) {
    float4 aL[8], bL[8];
#pragma unroll
    for (int it = 0; it < 8; ++it) {
      int r = it * 16 + rb;
      aL[it] = *reinterpret_cast<const float4*>(A + (size_t)(row0 + r) * lda + kt + c4 * 4);
      if (GUARDB) {
        int k0 = kt + c4 * 4;
        const float* bp = Bt + (size_t)(col0 + r) * ldb;
        bL[it].x = (k0 + 0 < Kb) ? bp[k0 + 0] : 0.f;
        bL[it].y = (k0 + 1 < Kb) ? bp[k0 + 1] : 0.f;
        bL[it].z = (k0 + 2 < Kb) ? bp[k0 + 2] : 0.f;
        bL[it].w = (k0 + 3 < Kb) ? bp[k0 + 3] : 0.f;
      } else {
        bL[it] = *reinterpret_cast<const float4*>(Bt + (size_t)(col0 + r) * ldb + kt + c4 * 4);
      }
    }
    __syncthreads();
#pragma unroll
    for (int it = 0; it < 8; ++it) {
      int r = it * 16 + rb;
      ushort4 av = make_ushort4(f2b(aL[it].x), f2b(aL[it].y), f2b(aL[it].z), f2b(aL[it].w));
      ushort4 bv = make_ushort4(f2b(bL[it].x), f2b(bL[it].y), f2b(bL[it].z), f2b(bL[it].w));
      *reinterpret_cast<ushort4*>(&As[r * 72 + c4 * 4]) = av;
      *reinterpret_cast<ushort4*>(&Bs[r * 72 + c4 * 4]) = bv;
    }
    __syncthreads();
#pragma unroll
    for (int kk = 0; kk < 2; ++kk) {
      const int ko = (lane >> 4) * 8 + kk * 32;
      short8 af[4], bf[4];
#pragma unroll
      for (int mi = 0; mi < 4; ++mi)
        af[mi] = *reinterpret_cast<const short8*>(&As[(wr + mi * 16 + (lane & 15)) * 72 + ko]);
#pragma unroll
      for (int ni = 0; ni < 4; ++ni)
        bf[ni] = *reinterpret_cast<const short8*>(&Bs[(wc + ni * 16 + (lane & 15)) * 72 + ko]);
#pragma unroll
      for (int mi = 0; mi < 4; ++mi)
#pragma unroll
        for (int ni = 0; ni < 4; ++ni)
          acc[mi][ni] = __builtin_amdgcn_mfma_f32_16x16x32_bf16(af[mi], bf[ni], acc[mi][ni], 0, 0, 0);
    }
  }

  if (EPI == 0 || EPI == 2) {
#pragma unroll
    for (int mi = 0; mi < 4; ++mi) {
      int rloc = wr + mi * 16 + (lane >> 4) * 4;
#pragma unroll
      for (int ni = 0; ni < 4; ++ni) {
        int cg = col0 + wc + ni * 16 + (lane & 15);
        float bv = bias ? bias[cg] : 0.f;
#pragma unroll
        for (int q = 0; q < 4; ++q) {
          float v = acc[mi][ni][q] + bv;
          if (EPI == 2) v = fmaxf(v, 0.f);
          C[(size_t)(row0 + rloc + q) * ldc + cg] = v;
        }
      }
    }
  } else {
    float rs[4][4];
#pragma unroll
    for (int mi = 0; mi < 4; ++mi) {
#pragma unroll
      for (int q = 0; q < 4; ++q) {
        int m = row0 + wr + mi * 16 + (lane >> 4) * 4 + q;
        int b = m & (BAT - 1);
        float v = 0.f;
#pragma unroll
        for (int ni = 0; ni < 4; ++ni) {
          int cg = col0 + wc + ni * 16 + (lane & 15);
          float e = acc[mi][ni][q] + bias[cg] + hws[(size_t)b * HID + cg];
          float sg = 1.f / (1.f + __expf(-e));
          v += sg * enw[cg];
        }
#pragma unroll
        for (int o = 1; o < 16; o <<= 1) v += __shfl_xor(v, o);
        rs[mi][q] = v;
      }
    }
    if ((lane & 15) == 0) {
#pragma unroll
      for (int mi = 0; mi < 4; ++mi)
#pragma unroll
        for (int q = 0; q < 4; ++q)
          ep[wave & 1][wr + mi * 16 + (lane >> 4) * 4 + q] = rs[mi][q];
    }
    __syncthreads();
    if (tid < 128)
      epart[(size_t)blockIdx.y * M + row0 + tid] = ep[0][tid] + ep[1][tid];
  }
}

// ---------------- conversion kernels ----------------
__global__ void f2b_kernel(const float* __restrict__ in, ushort* __restrict__ out, size_t n) {
  size_t i = ((size_t)blockIdx.x * 256 + threadIdx.x) * 8;
  if (i + 8 > n) return;
  float4 a = *reinterpret_cast<const float4*>(in + i);
  float4 b = *reinterpret_cast<const float4*>(in + i + 4);
  ushort o[8] = {f2b(a.x), f2b(a.y), f2b(a.z), f2b(a.w),
                 f2b(b.x), f2b(b.y), f2b(b.z), f2b(b.w)};
  *reinterpret_cast<short8*>(out + i) = *reinterpret_cast<short8*>(o);
}

// fused conversion of all small weight tensors (block-range partitioned)
__global__ void conv_weights(const float* __restrict__ hw, const float* __restrict__ whh,
                             const float* __restrict__ ew, const float* __restrict__ o1w,
                             const float* __restrict__ ldh,
                             ushort* __restrict__ whgh, ushort* __restrict__ ewb,
                             ushort* __restrict__ o1b, ushort* __restrict__ ldhb) {
  int blk = blockIdx.x;
  const float* src; ushort* dst; size_t off;
  if (blk < 512)        { src = hw;  dst = whgh;            off = (size_t)blk * 2048; }
  else if (blk < 2048)  { src = whh; dst = whgh + 1048576;  off = (size_t)(blk - 512) * 2048; }
  else if (blk < 2560)  { src = ew;  dst = ewb;             off = (size_t)(blk - 2048) * 2048; }
  else if (blk < 3072)  { src = o1w; dst = o1b;             off = (size_t)(blk - 2560) * 2048; }
  else                  { src = ldh; dst = ldhb;            off = (size_t)(blk - 3072) * 2048; }
  size_t i = off + (size_t)threadIdx.x * 8;
  float4 a = *reinterpret_cast<const float4*>(src + i);
  float4 b = *reinterpret_cast<const float4*>(src + i + 4);
  ushort o[8] = {f2b(a.x), f2b(a.y), f2b(a.z), f2b(a.w),
                 f2b(b.x), f2b(b.y), f2b(b.z), f2b(b.w)};
  *reinterpret_cast<short8*>(dst + i) = *reinterpret_cast<short8*>(o);
}

__global__ void pack_wih(const float* __restrict__ in, ushort* __restrict__ out) {
  int r = blockIdx.x;
  int c = blockIdx.y * 256 + threadIdx.x;
  if (c < 1088)
    out[(size_t)r * 1088 + c] = (c < 1027) ? f2b(in[(size_t)r * 1027 + c]) : (ushort)0;
}

// ---------------- small fused kernels ----------------
__global__ void softmax_kernel(const float* __restrict__ epart, int ntiles,
                               float* __restrict__ wsm, float* __restrict__ att) {
  int b = blockIdx.x, s = threadIdx.x;
  float e = 0.f;
  for (int nt = 0; nt < ntiles; ++nt) e += epart[(size_t)nt * (SEQ * BAT) + s * BAT + b];
  float m = e;
  for (int o = 1; o < 64; o <<= 1) m = fmaxf(m, __shfl_xor(m, o));
  __shared__ float rm[4], rsum[4];
  if ((s & 63) == 0) rm[s >> 6] = m;
  __syncthreads();
  m = fmaxf(fmaxf(rm[0], rm[1]), fmaxf(rm[2], rm[3]));
  float ex = __expf(e - m);
  float sum = ex;
  for (int o = 1; o < 64; o <<= 1) sum += __shfl_xor(sum, o);
  if ((s & 63) == 0) rsum[s >> 6] = sum;
  __syncthreads();
  sum = rsum[0] + rsum[1] + rsum[2] + rsum[3];
  float w = ex / sum;
  wsm[s * BAT + b] = w;
  att[b * SEQ + s] = w;
}

// gin palette cols + pad, and bias concat for merged h|gh GEMM
__global__ void prep_small(const float* __restrict__ pal, ushort* __restrict__ ginb,
                           const float* __restrict__ h_b, const float* __restrict__ b_hh,
                           float* __restrict__ bias_cat) {
  int t = threadIdx.x;
  ginb[t * 1088 + 0] = f2b(pal[t * 3 + 0]);
  ginb[t * 1088 + 1] = f2b(pal[t * 3 + 1]);
  ginb[t * 1088 + 2] = f2b(pal[t * 3 + 2]);
  for (int k = 1027; k < 1088; ++k) ginb[t * 1088 + k] = 0;
  for (int j = t; j < 4096; j += 256) bias_cat[j] = (j < 1024) ? h_b[j] : b_hh[j - 1024];
}

__global__ void prep_gin(const float* __restrict__ pal, float* __restrict__ gin) {
  int b = threadIdx.x;
  gin[b * 1088 + 0] = pal[b * 3 + 0];
  gin[b * 1088 + 1] = pal[b * 3 + 1];
  gin[b * 1088 + 2] = pal[b * 3 + 2];
  for (int k = 1027; k < 1088; ++k) gin[b * 1088 + k] = 0.f;
}

__global__ void context_bf(const ushort* __restrict__ encb, const float* __restrict__ wsm,
                           float* __restrict__ ctx, ushort* __restrict__ ginb) {
  int b = blockIdx.x, hc = blockIdx.y, t = threadIdx.x;
  __shared__ float wl[256];
  wl[t] = wsm[t * BAT + b];
  __syncthreads();
  int h = hc * 256 + t;
  const ushort* ep = encb + (size_t)b * HID + h;
  float c = 0.f;
#pragma unroll 8
  for (int s = 0; s < SEQ; ++s) c += wl[s] * b2f(ep[(size_t)s * BAT * HID]);
  ctx[(size_t)b * HID + h] = c;
  ginb[b * 1088 + 3 + h] = f2b(c);
}

__global__ void context_kernel(const float* __restrict__ enc, const float* __restrict__ wsm,
                               float* __restrict__ ctx, float* __restrict__ gin) {
  int b = blockIdx.x, hc = blockIdx.y, t = threadIdx.x;
  __shared__ float wl[256];
  wl[t] = wsm[t * BAT + b];
  __syncthreads();
  int h = hc * 256 + t;
  const float* ep = enc + (size_t)b * HID + h;
  float c = 0.f;
#pragma unroll 8
  for (int s = 0; s < SEQ; ++s) c += wl[s] * ep[(size_t)s * BAT * HID];
  ctx[(size_t)b * HID + h] = c;
  gin[b * 1088 + 3 + h] = c;
}

// gi row-stride fixed 3072; gh pointer pre-offset, stride ghs
__global__ void gru_combine(const float* __restrict__ gi, const float* __restrict__ gh, int ghs,
                            const float* __restrict__ hprev, float* __restrict__ hout,
                            ushort* __restrict__ hb) {
  int idx = blockIdx.x * 256 + threadIdx.x;
  int b = idx >> 10, j = idx & 1023;
  size_t gib = (size_t)b * 3 * HID;
  size_t ghb = (size_t)b * ghs;
  float ir = gi[gib + j], iz = gi[gib + HID + j], in_ = gi[gib + 2 * HID + j];
  float hr = gh[ghb + j], hz = gh[ghb + HID + j], hn = gh[ghb + 2 * HID + j];
  float r = 1.f / (1.f + __expf(-(ir + hr)));
  float z = 1.f / (1.f + __expf(-(iz + hz)));
  float n = tanhf(in_ + r * hn);
  float v = (1.f - z) * n + z * hprev[idx];
  hout[idx] = v;
  if (hb) hb[idx] = f2b(v);
}

__global__ void bn_stats(const float* __restrict__ x1, const float* __restrict__ bnw,
                         const float* __restrict__ bnb, float* __restrict__ sj,
                         float* __restrict__ tj) {
  int j = blockIdx.x * 256 + threadIdx.x;
  float s = 0.f, ss = 0.f;
  for (int b = 0; b < BAT; ++b) {
    float x = x1[(size_t)b * HID + j];
    s += x; ss += x * x;
  }
  float mu = s * (1.f / BAT);
  float var = ss * (1.f / BAT) - mu * mu;
  float rstd = rsqrtf(var + BNEPS);
  float sc = bnw[j] * rstd;
  sj[j] = sc;
  tj[j] = bnb[j] - mu * sc;
}

__global__ void palette_kernel(const float* __restrict__ x1, const float* __restrict__ sj,
                               const float* __restrict__ tj, const float* __restrict__ w2,
                               const float* __restrict__ b2, float* __restrict__ outp) {
  int b = blockIdx.x, t = threadIdx.x;
  float p0 = 0.f, p1 = 0.f, p2 = 0.f;
  for (int j = t; j < HID; j += 256) {
    float xn = x1[(size_t)b * HID + j] * sj[j] + tj[j];
    p0 += xn * w2[j];
    p1 += xn * w2[HID + j];
    p2 += xn * w2[2 * HID + j];
  }
  for (int o = 1; o < 64; o <<= 1) {
    p0 += __shfl_xor(p0, o); p1 += __shfl_xor(p1, o); p2 += __shfl_xor(p2, o);
  }
  __shared__ float r0[4], r1[4], r2[4];
  int w = t >> 6;
  if ((t & 63) == 0) { r0[w] = p0; r1[w] = p1; r2[w] = p2; }
  __syncthreads();
  if (t == 0) {
    outp[b * 3 + 0] = r0[0] + r0[1] + r0[2] + r0[3] + b2[0];
    outp[b * 3 + 1] = r1[0] + r1[1] + r1[2] + r1[3] + b2[1];
    outp[b * 3 + 2] = r2[0] + r2[1] + r2[2] + r2[3] + b2[2];
  }
}

extern "C" void kernel_launch(void* const* d_in, const int* in_sizes, int n_in,
                              void* d_out, int out_size, void* d_ws, size_t ws_size,
                              hipStream_t stream) {
  const float* pal_in = (const float*)d_in[0];
  const float* ldh    = (const float*)d_in[1];
  const float* enc    = (const float*)d_in[2];
  const float* e_w    = (const float*)d_in[3];
  const float* e_b    = (const float*)d_in[4];
  const float* h_w    = (const float*)d_in[5];
  const float* h_b    = (const float*)d_in[6];
  const float* en_w   = (const float*)d_in[7];
  const float* w_ih   = (const float*)d_in[9];
  const float* w_hh   = (const float*)d_in[10];
  const float* b_ih   = (const float*)d_in[11];
  const float* b_hh   = (const float*)d_in[12];
  const float* o1_w   = (const float*)d_in[13];
  const float* o1_b   = (const float*)d_in[14];
  const float* bnw    = (const float*)d_in[15];
  const float* bnb    = (const float*)d_in[16];
  const float* o2_w   = (const float*)d_in[17];
  const float* o2_b   = (const float*)d_in[18];

  float* out = (float*)d_out;
  float* out_pal = out;
  float* out_ctx = out + BAT * PAL;
  float* out_hid = out_ctx + BAT * HID;
  float* out_att = out_hid + BAT * HID;

  dim3 blk(256);

  char* p0 = (char*)d_ws;
  char* p = p0;
  auto carve = [&](size_t bytes) { char* r = p; p += (bytes + 255) & ~(size_t)255; return r; };
  ushort* enc_bf  = (ushort*)carve((size_t)SEQ * BAT * HID * 2);
  ushort* whgh_bf = (ushort*)carve((size_t)4 * HID * HID * 2);   // [h_w ; w_hh] rows
  ushort* ew_bf   = (ushort*)carve((size_t)HID * HID * 2);
  ushort* wih_bf  = (ushort*)carve((size_t)3 * HID * 1088 * 2);
  ushort* o1_bf   = (ushort*)carve((size_t)HID * HID * 2);
  ushort* ldh_bf  = (ushort*)carve((size_t)BAT * HID * 2);
  ushort* gin_bf  = (ushort*)carve((size_t)BAT * 1088 * 2);
  ushort* hid_bf  = (ushort*)carve((size_t)BAT * HID * 2);
  float* hgh      = (float*)carve((size_t)BAT * 4 * HID * 4);    // [h | gh(3H)] per row
  float* bias_cat = (float*)carve((size_t)4 * HID * 4);
  float* epart    = (float*)carve((size_t)4 * SEQ * BAT * 4);
  float* wsm      = (float*)carve((size_t)SEQ * BAT * 4);
  float* gi       = (float*)carve((size_t)BAT * 3 * HID * 4);
  float* x1       = (float*)carve((size_t)BAT * HID * 4);
  float* sj       = (float*)carve((size_t)HID * 4);
  float* tj       = (float*)carve((size_t)HID * 4);
  size_t need = (size_t)(p - p0);

  if (ws_size >= need) {
    conv_weights<<<dim3(3200), blk, 0, stream>>>(h_w, w_hh, e_w, o1_w, ldh,
                                                 whgh_bf, ew_bf, o1_bf, ldh_bf);
    pack_wih<<<dim3(3 * HID, 5), blk, 0, stream>>>(w_ih, wih_bf);
    prep_small<<<dim3(1), blk, 0, stream>>>(pal_in, gin_bf, h_b, b_hh, bias_cat);
    // merged [h | gh] = ldh @ [h_w ; w_hh].T + [h_b ; b_hh]
    gemm_bf<0><<<dim3(2, 32), blk, 0, stream>>>(
        ldh_bf, HID, whgh_bf, HID, bias_cat, hgh, 4 * HID, BAT, HID);
    f2b_kernel<<<dim3((SEQ * BAT * HID) / 2048), blk, 0, stream>>>(enc, enc_bf, (size_t)SEQ * BAT * HID);
    // energy partials: 256x256 8-phase kernel (grid 256 row-tiles x 4 col-tiles)
    gemm256_energy<16><<<dim3(1024), dim3(512), 0, stream>>>(
        enc_bf, ew_bf, e_b, hgh, 4 * HID, en_w, epart, SEQ * BAT);
    softmax_kernel<<<dim3(256), blk, 0, stream>>>(epart, 4, wsm, out_att);
    context_bf<<<dim3(256, 4), blk, 0, stream>>>(enc_bf, wsm, out_ctx, gin_bf);
    gemm_bf<0><<<dim3(2, 24), blk, 0, stream>>>(
        gin_bf, 1088, wih_bf, 1088, b_ih, gi, 3 * HID, BAT, 1088);
    gru_combine<<<dim3(1024), blk, 0, stream>>>(gi, hgh + HID, 4 * HID, ldh, out_hid, hid_bf);
    gemm_bf<2><<<dim3(2, 8), blk, 0, stream>>>(
        hid_bf, HID, o1_bf, HID, o1_b, x1, HID, BAT, HID);
    bn_stats<<<dim3(4), blk, 0, stream>>>(x1, bnw, bnb, sj, tj);
    palette_kernel<<<dim3(256), blk, 0, stream>>>(x1, sj, tj, o2_w, o2_b, out_pal);
  } else {
    // -------- fp32 fallback path --------
    char* q = p0;
    auto carve2 = [&](size_t bytes) { char* r = q; q += (bytes + 255) & ~(size_t)255; return r; };
    float* hws2   = (float*)carve2((size_t)BAT * HID * 4);
    float* epart2 = (float*)carve2((size_t)8 * SEQ * BAT * 4);
    float* wsm2   = (float*)carve2((size_t)SEQ * BAT * 4);
    float* gin2   = (float*)carve2((size_t)BAT * 1088 * 4);
    float* gi2    = (float*)carve2((size_t)BAT * 3 * HID * 4);
    float* gh2    = (float*)carve2((size_t)BAT * 3 * HID * 4);
    float* x12    = (float*)carve2((size_t)BAT * HID * 4);
    float* sj2    = (float*)carve2((size_t)HID * 4);
    float* tj2    = (float*)carve2((size_t)HID * 4);

    gemm_bt<0, false><<<dim3(2, 8), blk, 0, stream>>>(
        ldh, HID, h_w, HID, HID, h_b, hws2, HID, BAT, HID, nullptr, nullptr, nullptr);
    gemm_bt<1, false><<<dim3(512, 8), blk, 0, stream>>>(
        enc, HID, e_w, HID, HID, e_b, nullptr, 0, SEQ * BAT, HID, hws2, en_w, epart2);
    gemm_bt<0, false><<<dim3(2, 24), blk, 0, stream>>>(
        ldh, HID, w_hh, HID, HID, b_hh, gh2, 3 * HID, BAT, HID, nullptr, nullptr, nullptr);
    softmax_kernel<<<dim3(256), blk, 0, stream>>>(epart2, 8, wsm2, out_att);
    prep_gin<<<dim3(1), blk, 0, stream>>>(pal_in, gin2);
    context_kernel<<<dim3(256, 4), blk, 0, stream>>>(enc, wsm2, out_ctx, gin2);
    gemm_bt<0, true><<<dim3(2, 24), blk, 0, stream>>>(
        gin2, 1088, w_ih, 1027, 1027, b_ih, gi2, 3 * HID, BAT, 1088, nullptr, nullptr, nullptr);
    gru_combine<<<dim3(1024), blk, 0, stream>>>(gi2, gh2, 3 * HID, ldh, out_hid, nullptr);
    gemm_bt<2, false><<<dim3(2, 8), blk, 0, stream>>>(
        out_hid, HID, o1_w, HID, HID, o1_b, x12, HID, BAT, HID, nullptr, nullptr, nullptr);
    bn_stats<<<dim3(4), blk, 0, stream>>>(x12, bnw, bnb, sj2, tj2);
    palette_kernel<<<dim3(256), blk, 0, stream>>>(x12, sj2, tj2, o2_w, o2_b, out_pal);
  }
}

// Round 4
// 428.507 us; speedup vs baseline: 2.5313x; 1.0552x over previous
//
#include <hip/hip_runtime.h>
#include <hip/hip_bf16.h>
#include <cstdint>

#define HID 1024
#define PAL 3
#define SEQ 256
#define BAT 256
#define BNEPS 1e-5f

typedef __attribute__((ext_vector_type(8))) short short8;
typedef __attribute__((ext_vector_type(4))) float floatx4;

__device__ __forceinline__ ushort f2b(float f) {
  union { float f; uint32_t u; } v; v.f = f;
  uint32_t r = (v.u + 0x7FFFu + ((v.u >> 16) & 1u)) >> 16;
  return (ushort)r;
}
__device__ __forceinline__ float b2f(ushort u) {
  union { uint32_t u; float f; } v; v.u = ((uint32_t)u) << 16; return v.f;
}
__device__ __forceinline__ void gl_lds16(const ushort* g, ushort* l) {
  __builtin_amdgcn_global_load_lds(
      (const __attribute__((address_space(1))) void*)g,
      (__attribute__((address_space(3))) void*)l, 16, 0, 0);
}
__device__ __forceinline__ void cfence() { asm volatile("" ::: "memory"); }

// ================= 256x256 8-phase energy GEMM, A tri-buffered ================
// A: [M][K] bf16 (enc, HBM-streamed), Bt: [N][K] bf16 (e_w, L2-resident).
// Per-tile schedule (4 phases, 16 MFMA each):
//   g0: read bf(t)[8] + af01(t); (no stage)
//   g1: read af23(t); stage B(t+1)H0   <- single B buffer; safe: all B(t) reads
//                                         drained before end-of-g0 barrier
//   g2: read af45(t); stage B(t+1)H1 + A(t+2)H0  -> A buf (t+2)%3
//   g3: read af67(t); stage A(t+2)H1; MFMA; vmcnt(4)
// Issue order per tile: B(t+1)[4], A(t+2)[4] (monotone). At the g3 wait,
// outstanding = A(t+1)[4] + B(t+1)[4] + A(t+2)[4]; vmcnt(4) waits oldest 8 =
// exactly {A(t+1), B(t+1)} = next tile's needs, keeps A(t+2) in flight with
// ~5-6 phases of slack (> HBM latency). B slack 2-3 phases (> L2 latency).
template<int NT>
__global__ __launch_bounds__(512, 1)
void gemm256_energy(const ushort* __restrict__ A, const ushort* __restrict__ Bt,
                    const float* __restrict__ e_b, const float* __restrict__ hws, int ldh,
                    const float* __restrict__ enw, float* __restrict__ epart, int M)
{
  __shared__ ushort A_s[3][2][128 * 64];   // 96 KB: tri-buffer x half
  __shared__ ushort B_s[2][128 * 64];      // 32 KB: single buffer x half
  const int K = NT * 64;
  const int tid = threadIdx.x;
  const int lane = tid & 63;
  const int wave = tid >> 6;
  const int l15 = lane & 15;
  const int wm = wave >> 2, wn = wave & 3;

  // T1: bijective XCD swizzle (nwg divisible by 8)
  int bid = blockIdx.x;
  int swz = (bid & 7) * ((int)gridDim.x >> 3) + (bid >> 3);
  int rt = swz >> 2, ct = swz & 3;
  const int row0 = rt * 256, col0 = ct * 256;

  auto stageA = [&](int buf, int t, int h) {
#pragma unroll
    for (int j = 0; j < 2; ++j) {
      int cidx = j * 512 + tid;
      int r = cidx >> 3, c8 = cidx & 7;
      const ushort* src = A + (size_t)(row0 + h * 128 + r) * K + t * 64 + ((c8 ^ (r & 7)) << 3);
      gl_lds16(src, &A_s[buf][h][(size_t)(j * 512 + wave * 64) * 8]);
    }
  };
  auto stageB = [&](int t, int h) {
#pragma unroll
    for (int j = 0; j < 2; ++j) {
      int cidx = j * 512 + tid;
      int r = cidx >> 3, c8 = cidx & 7;
      const ushort* src = Bt + (size_t)(col0 + h * 128 + r) * K + t * 64 + ((c8 ^ (r & 7)) << 3);
      gl_lds16(src, &B_s[h][(size_t)(j * 512 + wave * 64) * 8]);
    }
  };
  auto readA = [&](int buf, int mi, int kh) -> short8 {
    int row = mi * 16 + l15;
    int kc = (lane >> 4) + kh * 4;
    return *reinterpret_cast<const short8*>(&A_s[buf][wm][row * 64 + ((kc ^ (row & 7)) << 3)]);
  };
  auto readB = [&](int ni, int kh) -> short8 {
    int rr = (wn & 1) * 64 + ni * 16 + l15;
    int kc = (lane >> 4) + kh * 4;
    return *reinterpret_cast<const short8*>(&B_s[wn >> 1][rr * 64 + ((kc ^ (rr & 7)) << 3)]);
  };

  floatx4 acc[8][4] = {};

  // prologue: A(0)->buf0, A(1)->buf1, B(0); drain all
  stageA(0, 0, 0); stageA(0, 0, 1);
  stageA(1, 1, 0); stageA(1, 1, 1);
  stageB(0, 0);    stageB(0, 1);
  asm volatile("s_waitcnt vmcnt(0)" ::: "memory");
  cfence(); __builtin_amdgcn_s_barrier(); cfence();

  int ta = 0;  // t % 3
  for (int t = 0; t < NT; ++t) {
    short8 bfr[4][2];
#pragma unroll
    for (int g = 0; g < 4; ++g) {
      short8 af[2][2];
      if (g == 0) {
#pragma unroll
        for (int ni = 0; ni < 4; ++ni) { bfr[ni][0] = readB(ni, 0); bfr[ni][1] = readB(ni, 1); }
      }
#pragma unroll
      for (int mi = 0; mi < 2; ++mi) {
        af[mi][0] = readA(ta, g * 2 + mi, 0);
        af[mi][1] = readA(ta, g * 2 + mi, 1);
      }
      if (g == 1) {
        if (t + 1 < NT) stageB(t + 1, 0);
      } else if (g == 2) {
        if (t + 1 < NT) stageB(t + 1, 1);
        if (t + 2 < NT) { int a2 = ta + 2; if (a2 >= 3) a2 -= 3; stageA(a2, t + 2, 0); }
      } else if (g == 3) {
        if (t + 2 < NT) { int a2 = ta + 2; if (a2 >= 3) a2 -= 3; stageA(a2, t + 2, 1); }
      }
      cfence(); __builtin_amdgcn_s_barrier(); cfence();
      __builtin_amdgcn_s_setprio(1);
#pragma unroll
      for (int mi = 0; mi < 2; ++mi)
#pragma unroll
        for (int ni = 0; ni < 4; ++ni)
#pragma unroll
          for (int kh = 0; kh < 2; ++kh)
            acc[g * 2 + mi][ni] = __builtin_amdgcn_mfma_f32_16x16x32_bf16(
                af[mi][kh], bfr[ni][kh], acc[g * 2 + mi][ni], 0, 0, 0);
      __builtin_amdgcn_s_setprio(0);
      if (g == 3) {
        if (t + 2 < NT) asm volatile("s_waitcnt vmcnt(4)" ::: "memory");
        else            asm volatile("s_waitcnt vmcnt(0)" ::: "memory");
      }
      cfence(); __builtin_amdgcn_s_barrier(); cfence();
    }
    ta = (ta + 1 == 3) ? 0 : ta + 1;
  }

  // ---- energy epilogue: per-row sum over this block's 256 cols ----
  __syncthreads();
  float* epl = (float*)&A_s[0][0][0];    // [8 waves][128 rows]
#pragma unroll
  for (int mi = 0; mi < 8; ++mi)
#pragma unroll
    for (int q = 0; q < 4; ++q) {
      int rl = wm * 128 + mi * 16 + (lane >> 4) * 4 + q;  // row_local == batch index
      float v = 0.f;
#pragma unroll
      for (int ni = 0; ni < 4; ++ni) {
        int cg = col0 + wn * 64 + ni * 16 + l15;
        float e = acc[mi][ni][q] + e_b[cg] + hws[(size_t)rl * ldh + cg];
        v += enw[cg] * (1.f / (1.f + __expf(-e)));
      }
#pragma unroll
      for (int o = 1; o < 16; o <<= 1) v += __shfl_xor(v, o);
      if (l15 == 0) epl[(wm * 4 + wn) * 128 + mi * 16 + (lane >> 4) * 4 + q] = v;
    }
  __syncthreads();
  if (tid < 256) {
    int wmm = tid >> 7, r = tid & 127;
    float s = 0.f;
#pragma unroll
    for (int w = 0; w < 4; ++w) s += epl[(wmm * 4 + w) * 128 + r];
    epart[(size_t)ct * M + row0 + tid] = s;
  }
}

// ---------------- bf16 GEMM, m97 structure (small GEMMs) ----------------
template<int EPI>
__global__ __launch_bounds__(256, 2)
void gemm_bf(const ushort* __restrict__ A, int lda,
             const ushort* __restrict__ Bt, int ldb,
             const float* __restrict__ bias,
             float* __restrict__ C, int ldc,
             int M, int K)
{
  __shared__ ushort As[128 * 64];
  __shared__ ushort Bs[128 * 64];

  const int tid = threadIdx.x;
  const int lane = tid & 63;
  const int wave = tid >> 6;
  const int wr = (wave >> 1) * 64;
  const int wc = (wave & 1) * 64;
  const int row0 = blockIdx.x * 128;
  const int col0 = blockIdx.y * 128;

  floatx4 acc[4][4] = {};

  for (int kt = 0; kt < K; kt += 64) {
#pragma unroll
    for (int i = 0; i < 4; ++i) {
      int chunk = i * 256 + tid;
      int r = chunk >> 3, c8 = chunk & 7;
      gl_lds16(A + (size_t)(row0 + r) * lda + kt + c8 * 8,
               (ushort*)As + (size_t)(i * 256 + wave * 64) * 8);
      gl_lds16(Bt + (size_t)(col0 + r) * ldb + kt + c8 * 8,
               (ushort*)Bs + (size_t)(i * 256 + wave * 64) * 8);
    }
    __syncthreads();
#pragma unroll
    for (int kk = 0; kk < 2; ++kk) {
      const int ko = (lane >> 4) * 8 + kk * 32;
      short8 af[4], bf[4];
#pragma unroll
      for (int mi = 0; mi < 4; ++mi)
        af[mi] = *reinterpret_cast<const short8*>(&As[(wr + mi * 16 + (lane & 15)) * 64 + ko]);
#pragma unroll
      for (int ni = 0; ni < 4; ++ni)
        bf[ni] = *reinterpret_cast<const short8*>(&Bs[(wc + ni * 16 + (lane & 15)) * 64 + ko]);
#pragma unroll
      for (int mi = 0; mi < 4; ++mi)
#pragma unroll
        for (int ni = 0; ni < 4; ++ni)
          acc[mi][ni] = __builtin_amdgcn_mfma_f32_16x16x32_bf16(af[mi], bf[ni], acc[mi][ni], 0, 0, 0);
    }
    __syncthreads();
  }

#pragma unroll
  for (int mi = 0; mi < 4; ++mi) {
    int rloc = wr + mi * 16 + (lane >> 4) * 4;
#pragma unroll
    for (int ni = 0; ni < 4; ++ni) {
      int cg = col0 + wc + ni * 16 + (lane & 15);
      float bv = bias ? bias[cg] : 0.f;
#pragma unroll
      for (int q = 0; q < 4; ++q) {
        float v = acc[mi][ni][q] + bv;
        if (EPI == 2) v = fmaxf(v, 0.f);
        C[(size_t)(row0 + rloc + q) * ldc + cg] = v;
      }
    }
  }
}

// ---------------- fp32-input GEMM (fallback path only) ----------------
template<int EPI, bool GUARDB>
__global__ __launch_bounds__(256, 2)
void gemm_bt(const float* __restrict__ A, int lda,
             const float* __restrict__ Bt, int ldb, int Kb,
             const float* __restrict__ bias,
             float* __restrict__ C, int ldc,
             int M, int K,
             const float* __restrict__ hws,
             const float* __restrict__ enw,
             float* __restrict__ epart)
{
  __shared__ ushort As[128 * 72];
  __shared__ ushort Bs[128 * 72];
  __shared__ float ep[2][128];

  const int tid = threadIdx.x;
  const int lane = tid & 63;
  const int wave = tid >> 6;
  const int wr = (wave >> 1) * 64;
  const int wc = (wave & 1) * 64;
  const int row0 = blockIdx.x * 128;
  const int col0 = blockIdx.y * 128;
  const int rb = tid >> 4;
  const int c4 = tid & 15;

  floatx4 acc[4][4] = {};

  for (int kt = 0; kt < K; kt += 64) {
    float4 aL[8], bL[8];
#pragma unroll
    for (int it = 0; it < 8; ++it) {
      int r = it * 16 + rb;
      aL[it] = *reinterpret_cast<const float4*>(A + (size_t)(row0 + r) * lda + kt + c4 * 4);
      if (GUARDB) {
        int k0 = kt + c4 * 4;
        const float* bp = Bt + (size_t)(col0 + r) * ldb;
        bL[it].x = (k0 + 0 < Kb) ? bp[k0 + 0] : 0.f;
        bL[it].y = (k0 + 1 < Kb) ? bp[k0 + 1] : 0.f;
        bL[it].z = (k0 + 2 < Kb) ? bp[k0 + 2] : 0.f;
        bL[it].w = (k0 + 3 < Kb) ? bp[k0 + 3] : 0.f;
      } else {
        bL[it] = *reinterpret_cast<const float4*>(Bt + (size_t)(col0 + r) * ldb + kt + c4 * 4);
      }
    }
    __syncthreads();
#pragma unroll
    for (int it = 0; it < 8; ++it) {
      int r = it * 16 + rb;
      ushort4 av = make_ushort4(f2b(aL[it].x), f2b(aL[it].y), f2b(aL[it].z), f2b(aL[it].w));
      ushort4 bv = make_ushort4(f2b(bL[it].x), f2b(bL[it].y), f2b(bL[it].z), f2b(bL[it].w));
      *reinterpret_cast<ushort4*>(&As[r * 72 + c4 * 4]) = av;
      *reinterpret_cast<ushort4*>(&Bs[r * 72 + c4 * 4]) = bv;
    }
    __syncthreads();
#pragma unroll
    for (int kk = 0; kk < 2; ++kk) {
      const int ko = (lane >> 4) * 8 + kk * 32;
      short8 af[4], bf[4];
#pragma unroll
      for (int mi = 0; mi < 4; ++mi)
        af[mi] = *reinterpret_cast<const short8*>(&As[(wr + mi * 16 + (lane & 15)) * 72 + ko]);
#pragma unroll
      for (int ni = 0; ni < 4; ++ni)
        bf[ni] = *reinterpret_cast<const short8*>(&Bs[(wc + ni * 16 + (lane & 15)) * 72 + ko]);
#pragma unroll
      for (int mi = 0; mi < 4; ++mi)
#pragma unroll
        for (int ni = 0; ni < 4; ++ni)
          acc[mi][ni] = __builtin_amdgcn_mfma_f32_16x16x32_bf16(af[mi], bf[ni], acc[mi][ni], 0, 0, 0);
    }
  }

  if (EPI == 0 || EPI == 2) {
#pragma unroll
    for (int mi = 0; mi < 4; ++mi) {
      int rloc = wr + mi * 16 + (lane >> 4) * 4;
#pragma unroll
      for (int ni = 0; ni < 4; ++ni) {
        int cg = col0 + wc + ni * 16 + (lane & 15);
        float bv = bias ? bias[cg] : 0.f;
#pragma unroll
        for (int q = 0; q < 4; ++q) {
          float v = acc[mi][ni][q] + bv;
          if (EPI == 2) v = fmaxf(v, 0.f);
          C[(size_t)(row0 + rloc + q) * ldc + cg] = v;
        }
      }
    }
  } else {
    float rs[4][4];
#pragma unroll
    for (int mi = 0; mi < 4; ++mi) {
#pragma unroll
      for (int q = 0; q < 4; ++q) {
        int m = row0 + wr + mi * 16 + (lane >> 4) * 4 + q;
        int b = m & (BAT - 1);
        float v = 0.f;
#pragma unroll
        for (int ni = 0; ni < 4; ++ni) {
          int cg = col0 + wc + ni * 16 + (lane & 15);
          float e = acc[mi][ni][q] + bias[cg] + hws[(size_t)b * HID + cg];
          float sg = 1.f / (1.f + __expf(-e));
          v += sg * enw[cg];
        }
#pragma unroll
        for (int o = 1; o < 16; o <<= 1) v += __shfl_xor(v, o);
        rs[mi][q] = v;
      }
    }
    if ((lane & 15) == 0) {
#pragma unroll
      for (int mi = 0; mi < 4; ++mi)
#pragma unroll
        for (int q = 0; q < 4; ++q)
          ep[wave & 1][wr + mi * 16 + (lane >> 4) * 4 + q] = rs[mi][q];
    }
    __syncthreads();
    if (tid < 128)
      epart[(size_t)blockIdx.y * M + row0 + tid] = ep[0][tid] + ep[1][tid];
  }
}

// ---------------- conversion kernels ----------------
__global__ void f2b_kernel(const float* __restrict__ in, ushort* __restrict__ out, size_t n) {
  size_t i = ((size_t)blockIdx.x * 256 + threadIdx.x) * 8;
  if (i + 8 > n) return;
  float4 a = *reinterpret_cast<const float4*>(in + i);
  float4 b = *reinterpret_cast<const float4*>(in + i + 4);
  ushort o[8] = {f2b(a.x), f2b(a.y), f2b(a.z), f2b(a.w),
                 f2b(b.x), f2b(b.y), f2b(b.z), f2b(b.w)};
  *reinterpret_cast<short8*>(out + i) = *reinterpret_cast<short8*>(o);
}

// fused conversion of all small weight tensors (block-range partitioned)
__global__ void conv_weights(const float* __restrict__ hw, const float* __restrict__ whh,
                             const float* __restrict__ ew, const float* __restrict__ o1w,
                             const float* __restrict__ ldh,
                             ushort* __restrict__ whgh, ushort* __restrict__ ewb,
                             ushort* __restrict__ o1b, ushort* __restrict__ ldhb) {
  int blk = blockIdx.x;
  const float* src; ushort* dst; size_t off;
  if (blk < 512)        { src = hw;  dst = whgh;            off = (size_t)blk * 2048; }
  else if (blk < 2048)  { src = whh; dst = whgh + 1048576;  off = (size_t)(blk - 512) * 2048; }
  else if (blk < 2560)  { src = ew;  dst = ewb;             off = (size_t)(blk - 2048) * 2048; }
  else if (blk < 3072)  { src = o1w; dst = o1b;             off = (size_t)(blk - 2560) * 2048; }
  else                  { src = ldh; dst = ldhb;            off = (size_t)(blk - 3072) * 2048; }
  size_t i = off + (size_t)threadIdx.x * 8;
  float4 a = *reinterpret_cast<const float4*>(src + i);
  float4 b = *reinterpret_cast<const float4*>(src + i + 4);
  ushort o[8] = {f2b(a.x), f2b(a.y), f2b(a.z), f2b(a.w),
                 f2b(b.x), f2b(b.y), f2b(b.z), f2b(b.w)};
  *reinterpret_cast<short8*>(dst + i) = *reinterpret_cast<short8*>(o);
}

__global__ void pack_wih(const float* __restrict__ in, ushort* __restrict__ out) {
  int r = blockIdx.x;
  int c = blockIdx.y * 256 + threadIdx.x;
  if (c < 1088)
    out[(size_t)r * 1088 + c] = (c < 1027) ? f2b(in[(size_t)r * 1027 + c]) : (ushort)0;
}

// ---------------- small fused kernels ----------------
__global__ void softmax_kernel(const float* __restrict__ epart, int ntiles,
                               float* __restrict__ wsm, float* __restrict__ att) {
  int b = blockIdx.x, s = threadIdx.x;
  float e = 0.f;
  for (int nt = 0; nt < ntiles; ++nt) e += epart[(size_t)nt * (SEQ * BAT) + s * BAT + b];
  float m = e;
  for (int o = 1; o < 64; o <<= 1) m = fmaxf(m, __shfl_xor(m, o));
  __shared__ float rm[4], rsum[4];
  if ((s & 63) == 0) rm[s >> 6] = m;
  __syncthreads();
  m = fmaxf(fmaxf(rm[0], rm[1]), fmaxf(rm[2], rm[3]));
  float ex = __expf(e - m);
  float sum = ex;
  for (int o = 1; o < 64; o <<= 1) sum += __shfl_xor(sum, o);
  if ((s & 63) == 0) rsum[s >> 6] = sum;
  __syncthreads();
  sum = rsum[0] + rsum[1] + rsum[2] + rsum[3];
  float w = ex / sum;
  wsm[s * BAT + b] = w;
  att[b * SEQ + s] = w;
}

// gin palette cols + pad, and bias concat for merged h|gh GEMM
__global__ void prep_small(const float* __restrict__ pal, ushort* __restrict__ ginb,
                           const float* __restrict__ h_b, const float* __restrict__ b_hh,
                           float* __restrict__ bias_cat) {
  int t = threadIdx.x;
  ginb[t * 1088 + 0] = f2b(pal[t * 3 + 0]);
  ginb[t * 1088 + 1] = f2b(pal[t * 3 + 1]);
  ginb[t * 1088 + 2] = f2b(pal[t * 3 + 2]);
  for (int k = 1027; k < 1088; ++k) ginb[t * 1088 + k] = 0;
  for (int j = t; j < 4096; j += 256) bias_cat[j] = (j < 1024) ? h_b[j] : b_hh[j - 1024];
}

__global__ void prep_gin(const float* __restrict__ pal, float* __restrict__ gin) {
  int b = threadIdx.x;
  gin[b * 1088 + 0] = pal[b * 3 + 0];
  gin[b * 1088 + 1] = pal[b * 3 + 1];
  gin[b * 1088 + 2] = pal[b * 3 + 2];
  for (int k = 1027; k < 1088; ++k) gin[b * 1088 + k] = 0.f;
}

// context: vectorized short8 loads (G13); 128 threads, one block per batch b
__global__ void context_bf(const ushort* __restrict__ encb, const float* __restrict__ wsm,
                           float* __restrict__ ctx, ushort* __restrict__ ginb) {
  int b = blockIdx.x, t = threadIdx.x;
  __shared__ float wl[256];
  wl[t] = wsm[t * BAT + b];
  wl[t + 128] = wsm[(t + 128) * BAT + b];
  __syncthreads();
  int h0 = t * 8;
  const ushort* ep = encb + (size_t)b * HID + h0;
  float c[8] = {};
#pragma unroll 8
  for (int s = 0; s < SEQ; ++s) {
    short8 v = *reinterpret_cast<const short8*>(ep + (size_t)s * BAT * HID);
    float w = wl[s];
#pragma unroll
    for (int j = 0; j < 8; ++j) c[j] += w * b2f((ushort)v[j]);
  }
  float4 lo = {c[0], c[1], c[2], c[3]};
  float4 hi = {c[4], c[5], c[6], c[7]};
  *reinterpret_cast<float4*>(ctx + (size_t)b * HID + h0) = lo;
  *reinterpret_cast<float4*>(ctx + (size_t)b * HID + h0 + 4) = hi;
#pragma unroll
  for (int j = 0; j < 8; ++j) ginb[b * 1088 + 3 + h0 + j] = f2b(c[j]);
}

__global__ void context_kernel(const float* __restrict__ enc, const float* __restrict__ wsm,
                               float* __restrict__ ctx, float* __restrict__ gin) {
  int b = blockIdx.x, hc = blockIdx.y, t = threadIdx.x;
  __shared__ float wl[256];
  wl[t] = wsm[t * BAT + b];
  __syncthreads();
  int h = hc * 256 + t;
  const float* ep = enc + (size_t)b * HID + h;
  float c = 0.f;
#pragma unroll 8
  for (int s = 0; s < SEQ; ++s) c += wl[s] * ep[(size_t)s * BAT * HID];
  ctx[(size_t)b * HID + h] = c;
  gin[b * 1088 + 3 + h] = c;
}

// gi row-stride fixed 3072; gh pointer pre-offset, stride ghs
__global__ void gru_combine(const float* __restrict__ gi, const float* __restrict__ gh, int ghs,
                            const float* __restrict__ hprev, float* __restrict__ hout,
                            ushort* __restrict__ hb) {
  int idx = blockIdx.x * 256 + threadIdx.x;
  int b = idx >> 10, j = idx & 1023;
  size_t gib = (size_t)b * 3 * HID;
  size_t ghb = (size_t)b * ghs;
  float ir = gi[gib + j], iz = gi[gib + HID + j], in_ = gi[gib + 2 * HID + j];
  float hr = gh[ghb + j], hz = gh[ghb + HID + j], hn = gh[ghb + 2 * HID + j];
  float r = 1.f / (1.f + __expf(-(ir + hr)));
  float z = 1.f / (1.f + __expf(-(iz + hz)));
  float n = tanhf(in_ + r * hn);
  float v = (1.f - z) * n + z * hprev[idx];
  hout[idx] = v;
  if (hb) hb[idx] = f2b(v);
}

__global__ void bn_stats(const float* __restrict__ x1, const float* __restrict__ bnw,
                         const float* __restrict__ bnb, float* __restrict__ sj,
                         float* __restrict__ tj) {
  int j = blockIdx.x * 256 + threadIdx.x;
  float s = 0.f, ss = 0.f;
  for (int b = 0; b < BAT; ++b) {
    float x = x1[(size_t)b * HID + j];
    s += x; ss += x * x;
  }
  float mu = s * (1.f / BAT);
  float var = ss * (1.f / BAT) - mu * mu;
  float rstd = rsqrtf(var + BNEPS);
  float sc = bnw[j] * rstd;
  sj[j] = sc;
  tj[j] = bnb[j] - mu * sc;
}

__global__ void palette_kernel(const float* __restrict__ x1, const float* __restrict__ sj,
                               const float* __restrict__ tj, const float* __restrict__ w2,
                               const float* __restrict__ b2, float* __restrict__ outp) {
  int b = blockIdx.x, t = threadIdx.x;
  float p0 = 0.f, p1 = 0.f, p2 = 0.f;
  for (int j = t; j < HID; j += 256) {
    float xn = x1[(size_t)b * HID + j] * sj[j] + tj[j];
    p0 += xn * w2[j];
    p1 += xn * w2[HID + j];
    p2 += xn * w2[2 * HID + j];
  }
  for (int o = 1; o < 64; o <<= 1) {
    p0 += __shfl_xor(p0, o); p1 += __shfl_xor(p1, o); p2 += __shfl_xor(p2, o);
  }
  __shared__ float r0[4], r1[4], r2[4];
  int w = t >> 6;
  if ((t & 63) == 0) { r0[w] = p0; r1[w] = p1; r2[w] = p2; }
  __syncthreads();
  if (t == 0) {
    outp[b * 3 + 0] = r0[0] + r0[1] + r0[2] + r0[3] + b2[0];
    outp[b * 3 + 1] = r1[0] + r1[1] + r1[2] + r1[3] + b2[1];
    outp[b * 3 + 2] = r2[0] + r2[1] + r2[2] + r2[3] + b2[2];
  }
}

extern "C" void kernel_launch(void* const* d_in, const int* in_sizes, int n_in,
                              void* d_out, int out_size, void* d_ws, size_t ws_size,
                              hipStream_t stream) {
  const float* pal_in = (const float*)d_in[0];
  const float* ldh    = (const float*)d_in[1];
  const float* enc    = (const float*)d_in[2];
  const float* e_w    = (const float*)d_in[3];
  const float* e_b    = (const float*)d_in[4];
  const float* h_w    = (const float*)d_in[5];
  const float* h_b    = (const float*)d_in[6];
  const float* en_w   = (const float*)d_in[7];
  const float* w_ih   = (const float*)d_in[9];
  const float* w_hh   = (const float*)d_in[10];
  const float* b_ih   = (const float*)d_in[11];
  const float* b_hh   = (const float*)d_in[12];
  const float* o1_w   = (const float*)d_in[13];
  const float* o1_b   = (const float*)d_in[14];
  const float* bnw    = (const float*)d_in[15];
  const float* bnb    = (const float*)d_in[16];
  const float* o2_w   = (const float*)d_in[17];
  const float* o2_b   = (const float*)d_in[18];

  float* out = (float*)d_out;
  float* out_pal = out;
  float* out_ctx = out + BAT * PAL;
  float* out_hid = out_ctx + BAT * HID;
  float* out_att = out_hid + BAT * HID;

  dim3 blk(256);

  char* p0 = (char*)d_ws;
  char* p = p0;
  auto carve = [&](size_t bytes) { char* r = p; p += (bytes + 255) & ~(size_t)255; return r; };
  ushort* enc_bf  = (ushort*)carve((size_t)SEQ * BAT * HID * 2);
  ushort* whgh_bf = (ushort*)carve((size_t)4 * HID * HID * 2);   // [h_w ; w_hh] rows
  ushort* ew_bf   = (ushort*)carve((size_t)HID * HID * 2);
  ushort* wih_bf  = (ushort*)carve((size_t)3 * HID * 1088 * 2);
  ushort* o1_bf   = (ushort*)carve((size_t)HID * HID * 2);
  ushort* ldh_bf  = (ushort*)carve((size_t)BAT * HID * 2);
  ushort* gin_bf  = (ushort*)carve((size_t)BAT * 1088 * 2);
  ushort* hid_bf  = (ushort*)carve((size_t)BAT * HID * 2);
  float* hgh      = (float*)carve((size_t)BAT * 4 * HID * 4);    // [h | gh(3H)] per row
  float* bias_cat = (float*)carve((size_t)4 * HID * 4);
  float* epart    = (float*)carve((size_t)4 * SEQ * BAT * 4);
  float* wsm      = (float*)carve((size_t)SEQ * BAT * 4);
  float* gi       = (float*)carve((size_t)BAT * 3 * HID * 4);
  float* x1       = (float*)carve((size_t)BAT * HID * 4);
  float* sj       = (float*)carve((size_t)HID * 4);
  float* tj       = (float*)carve((size_t)HID * 4);
  size_t need = (size_t)(p - p0);

  if (ws_size >= need) {
    conv_weights<<<dim3(3200), blk, 0, stream>>>(h_w, w_hh, e_w, o1_w, ldh,
                                                 whgh_bf, ew_bf, o1_bf, ldh_bf);
    pack_wih<<<dim3(3 * HID, 5), blk, 0, stream>>>(w_ih, wih_bf);
    prep_small<<<dim3(1), blk, 0, stream>>>(pal_in, gin_bf, h_b, b_hh, bias_cat);
    // merged [h | gh] = ldh @ [h_w ; w_hh].T + [h_b ; b_hh]
    gemm_bf<0><<<dim3(2, 32), blk, 0, stream>>>(
        ldh_bf, HID, whgh_bf, HID, bias_cat, hgh, 4 * HID, BAT, HID);
    f2b_kernel<<<dim3((SEQ * BAT * HID) / 2048), blk, 0, stream>>>(enc, enc_bf, (size_t)SEQ * BAT * HID);
    // energy partials: 256x256 deep-pipelined kernel (grid 256 row-tiles x 4 col-tiles)
    gemm256_energy<16><<<dim3(1024), dim3(512), 0, stream>>>(
        enc_bf, ew_bf, e_b, hgh, 4 * HID, en_w, epart, SEQ * BAT);
    softmax_kernel<<<dim3(256), blk, 0, stream>>>(epart, 4, wsm, out_att);
    context_bf<<<dim3(256), dim3(128), 0, stream>>>(enc_bf, wsm, out_ctx, gin_bf);
    gemm_bf<0><<<dim3(2, 24), blk, 0, stream>>>(
        gin_bf, 1088, wih_bf, 1088, b_ih, gi, 3 * HID, BAT, 1088);
    gru_combine<<<dim3(1024), blk, 0, stream>>>(gi, hgh + HID, 4 * HID, ldh, out_hid, hid_bf);
    gemm_bf<2><<<dim3(2, 8), blk, 0, stream>>>(
        hid_bf, HID, o1_bf, HID, o1_b, x1, HID, BAT, HID);
    bn_stats<<<dim3(4), blk, 0, stream>>>(x1, bnw, bnb, sj, tj);
    palette_kernel<<<dim3(256), blk, 0, stream>>>(x1, sj, tj, o2_w, o2_b, out_pal);
  } else {
    // -------- fp32 fallback path --------
    char* q = p0;
    auto carve2 = [&](size_t bytes) { char* r = q; q += (bytes + 255) & ~(size_t)255; return r; };
    float* hws2   = (float*)carve2((size_t)BAT * HID * 4);
    float* epart2 = (float*)carve2((size_t)8 * SEQ * BAT * 4);
    float* wsm2   = (float*)carve2((size_t)SEQ * BAT * 4);
    float* gin2   = (float*)carve2((size_t)BAT * 1088 * 4);
    float* gi2    = (float*)carve2((size_t)BAT * 3 * HID * 4);
    float* gh2    = (float*)carve2((size_t)BAT * 3 * HID * 4);
    float* x12    = (float*)carve2((size_t)BAT * HID * 4);
    float* sj2    = (float*)carve2((size_t)HID * 4);
    float* tj2    = (float*)carve2((size_t)HID * 4);

    gemm_bt<0, false><<<dim3(2, 8), blk, 0, stream>>>(
        ldh, HID, h_w, HID, HID, h_b, hws2, HID, BAT, HID, nullptr, nullptr, nullptr);
    gemm_bt<1, false><<<dim3(512, 8), blk, 0, stream>>>(
        enc, HID, e_w, HID, HID, e_b, nullptr, 0, SEQ * BAT, HID, hws2, en_w, epart2);
    gemm_bt<0, false><<<dim3(2, 24), blk, 0, stream>>>(
        ldh, HID, w_hh, HID, HID, b_hh, gh2, 3 * HID, BAT, HID, nullptr, nullptr, nullptr);
    softmax_kernel<<<dim3(256), blk, 0, stream>>>(epart2, 8, wsm2, out_att);
    prep_gin<<<dim3(1), blk, 0, stream>>>(pal_in, gin2);
    context_kernel<<<dim3(256, 4), blk, 0, stream>>>(enc, wsm2, out_ctx, gin2);
    gemm_bt<0, true><<<dim3(2, 24), blk, 0, stream>>>(
        gin2, 1088, w_ih, 1027, 1027, b_ih, gi2, 3 * HID, BAT, 1088, nullptr, nullptr, nullptr);
    gru_combine<<<dim3(1024), blk, 0, stream>>>(gi2, gh2, 3 * HID, ldh, out_hid, nullptr);
    gemm_bt<2, false><<<dim3(2, 8), blk, 0, stream>>>(
        out_hid, HID, o1_w, HID, HID, o1_b, x12, HID, BAT, HID, nullptr, nullptr, nullptr);
    bn_stats<<<dim3(4), blk, 0, stream>>>(x12, bnw, bnb, sj2, tj2);
    palette_kernel<<<dim3(256), blk, 0, stream>>>(x12, sj2, tj2, o2_w, o2_b, out_pal);
  }
}